// Round 2
// baseline (8018.857 us; speedup 1.0000x reference)
//
#include <hip/hip_runtime.h>
#include <cstdint>
#include <cstddef>

// ---------------------------------------------------------------------------
// JAX threefry2x32 reproduction (20 rounds), host + device.
// jax.random.key(42) -> key data (0, 42)
// fold_in(key, i)    -> threefry((0,42), (0,i))
// partitionable random_bits (32-bit, default in modern JAX >=0.4.30):
//   bits1, bits2 = threefry(folded_key, (hi32(idx), lo32(idx)))
//   bit_width==64 -> (bits1<<32)|bits2 ; bit_width<64 -> XOR-fold: bits1^bits2
// uniform: u = bitcast((bits>>9)|0x3f800000) - 1.0f ;  keep iff u < 0.9f
// ---------------------------------------------------------------------------
#ifndef JAX_PARTITIONABLE
#define JAX_PARTITIONABLE 1
#endif
#ifndef JAX_PART_WORD      // 2 = o0^o1 (xor-fold), 0 = o0, 1 = o1
#define JAX_PART_WORD 2
#endif

__host__ __device__ inline void tf2x32(uint32_t k0, uint32_t k1,
                                       uint32_t x0, uint32_t x1,
                                       uint32_t* o0, uint32_t* o1)
{
    uint32_t ks2 = k0 ^ k1 ^ 0x1BD11BDAu;
    x0 += k0; x1 += k1;
#define TF_R(r) do { x0 += x1; x1 = (x1 << (r)) | (x1 >> (32 - (r))); x1 ^= x0; } while (0)
    TF_R(13); TF_R(15); TF_R(26); TF_R(6);
    x0 += k1;  x1 += ks2 + 1u;
    TF_R(17); TF_R(29); TF_R(16); TF_R(24);
    x0 += ks2; x1 += k0 + 2u;
    TF_R(13); TF_R(15); TF_R(26); TF_R(6);
    x0 += k0;  x1 += k1 + 3u;
    TF_R(17); TF_R(29); TF_R(16); TF_R(24);
    x0 += k1;  x1 += ks2 + 4u;
    TF_R(13); TF_R(15); TF_R(26); TF_R(6);
    x0 += ks2; x1 += k0 + 5u;
#undef TF_R
    *o0 = x0; *o1 = x1;
}

__device__ inline float drop_scale(uint32_t fk0, uint32_t fk1, uint32_t idx, uint32_t halfsz)
{
    uint32_t o0, o1, bits;
#if JAX_PARTITIONABLE
    tf2x32(fk0, fk1, 0u, idx, &o0, &o1);
#if JAX_PART_WORD == 2
    bits = o0 ^ o1;                  // XOR-fold of the two 32-bit words
#elif JAX_PART_WORD == 0
    bits = o0;
#else
    bits = o1;
#endif
#else
    if (idx < halfsz) { tf2x32(fk0, fk1, idx, idx + halfsz, &o0, &o1); bits = o0; }
    else              { tf2x32(fk0, fk1, idx - halfsz, idx, &o0, &o1); bits = o1; }
#endif
    float u = __uint_as_float((bits >> 9) | 0x3f800000u) - 1.0f;
    return (u < 0.9f) ? (1.0f / 0.9f) : 0.0f;
}

// ---------------------------------------------------------------------------
// Edge scatter: 32 lanes per edge, float4 per lane. agg += h[src], deg[dst]++.
// ---------------------------------------------------------------------------
__global__ __launch_bounds__(256) void scatter_add_kernel(
    const float* __restrict__ h, const int* __restrict__ src,
    const int* __restrict__ dst, float* __restrict__ agg,
    uint32_t* __restrict__ deg, int E)
{
    long long t = (long long)blockIdx.x * 256 + threadIdx.x;
    int e = (int)(t >> 5);
    if (e >= E) return;
    int c = ((int)t & 31) * 4;
    int s = src[e], d0 = dst[e];
    float4 v = *(const float4*)&h[(size_t)s * 128 + c];
    float* out = &agg[(size_t)d0 * 128 + c];
    unsafeAtomicAdd(out + 0, v.x);
    unsafeAtomicAdd(out + 1, v.y);
    unsafeAtomicAdd(out + 2, v.z);
    unsafeAtomicAdd(out + 3, v.w);
    if ((t & 31) == 0) atomicAdd(deg + d0, 1u);
}

// ---------------------------------------------------------------------------
// Type bucketing: histogram -> tiny scan -> scatter node ids
// ---------------------------------------------------------------------------
__global__ void count_types_kernel(const int* __restrict__ types,
                                   uint32_t* __restrict__ cnt, int n)
{
    int i = blockIdx.x * 256 + threadIdx.x;
    if (i < n) atomicAdd(&cnt[types[i]], 1u);
}

__global__ void scan_types_kernel(const uint32_t* __restrict__ cnt,
                                  int* __restrict__ off, uint32_t* __restrict__ cur)
{
    if (threadIdx.x == 0) {
        int a = 0;
        for (int t = 0; t < 8; ++t) { off[t] = a; cur[t] = (uint32_t)a; a += (int)cnt[t]; }
        off[8] = a;
    }
}

__global__ void fill_order_kernel(const int* __restrict__ types,
                                  uint32_t* __restrict__ cur,
                                  int* __restrict__ order, int n)
{
    int i = blockIdx.x * 256 + threadIdx.x;
    if (i < n) {
        uint32_t pos = atomicAdd(&cur[types[i]], 1u);
        order[pos] = i;
    }
}

// ---------------------------------------------------------------------------
// Per-type GEMM: out[n] = relu(agg[n]/max(deg,1) @ W[t] + b[t]) (* dropout)
// Block: 256 thr = 16(tn: 4 nodes each) x 16(tj: feats tj*4..+3 and 64+tj*4..+3)
// LDS: W[t] 128x132 (67.6KB) + A 64x132 (33.8KB) -> ~102KB, 1 block/CU
// ---------------------------------------------------------------------------
__global__ __launch_bounds__(256) void type_gemm_kernel(
    const float* __restrict__ agg, const uint32_t* __restrict__ deg,
    const int* __restrict__ order, const int* __restrict__ off,
    const float* __restrict__ convW, const float* __restrict__ convb,
    float* __restrict__ hout,
    int relu_act, int do_drop, uint32_t fk0, uint32_t fk1, uint32_t halfsz)
{
    __shared__ float WL[128 * 132];
    __shared__ float AL[64 * 132];
    __shared__ float SC[64];
    __shared__ int   ND[64];

    int t = blockIdx.y;
    int b0 = off[t] + blockIdx.x * 64;
    int bend = off[t + 1];
    if (b0 >= bend) return;
    int m = bend - b0; if (m > 64) m = 64;
    int tid = threadIdx.x;

    if (tid < 64) {
        if (tid < m) {
            int nd = order[b0 + tid];
            ND[tid] = nd;
            SC[tid] = 1.0f / fmaxf((float)deg[nd], 1.0f);
        } else { ND[tid] = -1; SC[tid] = 0.0f; }
    }
    __syncthreads();

    // stage W[t] (coalesced float4)
    const float* Wt = convW + (size_t)t * 16384;
    #pragma unroll
    for (int it = 0; it < 16; ++it) {
        int idx4 = (it * 256 + tid) * 4;
        int row = idx4 >> 7, col = idx4 & 127;
        *(float4*)&WL[row * 132 + col] = *(const float4*)&Wt[idx4];
    }
    // stage A rows (scaled by 1/deg), zero tail
    #pragma unroll
    for (int it = 0; it < 8; ++it) {
        int f4 = (it * 256 + tid) * 4;
        int i = f4 >> 7, k = f4 & 127;
        float4 v = make_float4(0.f, 0.f, 0.f, 0.f);
        int nd = ND[i];
        if (nd >= 0) {
            v = *(const float4*)&agg[(size_t)nd * 128 + k];
            float s = SC[i];
            v.x *= s; v.y *= s; v.z *= s; v.w *= s;
        }
        *(float4*)&AL[i * 132 + k] = v;
    }
    __syncthreads();

    int tn = tid >> 4, tj = tid & 15;
    float acc[4][8];
    #pragma unroll
    for (int a = 0; a < 4; ++a)
        #pragma unroll
        for (int b = 0; b < 8; ++b) acc[a][b] = 0.f;

    const float* A0 = &AL[(tn * 4) * 132];
    #pragma unroll 4
    for (int k = 0; k < 128; ++k) {
        float av[4];
        av[0] = A0[k]; av[1] = A0[132 + k]; av[2] = A0[264 + k]; av[3] = A0[396 + k];
        float4 w0 = *(const float4*)&WL[k * 132 + tj * 4];
        float4 w1 = *(const float4*)&WL[k * 132 + 64 + tj * 4];
        float wv[8] = { w0.x, w0.y, w0.z, w0.w, w1.x, w1.y, w1.z, w1.w };
        #pragma unroll
        for (int mi = 0; mi < 4; ++mi)
            #pragma unroll
            for (int q = 0; q < 8; ++q)
                acc[mi][q] += av[mi] * wv[q];
    }

    const float* bptr = convb + (size_t)t * 128;
    #pragma unroll
    for (int mi = 0; mi < 4; ++mi) {
        int nd = ND[tn * 4 + mi];
        if (nd < 0) continue;
        float o[8];
        #pragma unroll
        for (int q = 0; q < 8; ++q) {
            int j = (q < 4) ? (tj * 4 + q) : (64 + tj * 4 + (q - 4));
            float v = acc[mi][q] + bptr[j];
            if (relu_act) v = fmaxf(v, 0.f);
            if (do_drop) v *= drop_scale(fk0, fk1, (uint32_t)nd * 128u + (uint32_t)j, halfsz);
            o[q] = v;
        }
        *(float4*)&hout[(size_t)nd * 128 + tj * 4]      = make_float4(o[0], o[1], o[2], o[3]);
        *(float4*)&hout[(size_t)nd * 128 + 64 + tj * 4] = make_float4(o[4], o[5], o[6], o[7]);
    }
}

// ---------------------------------------------------------------------------
// Final FC: out[n] = h[n] @ fcW + fcb   (128 -> 64), 32 nodes per block
// ---------------------------------------------------------------------------
__global__ __launch_bounds__(256) void fc_kernel(
    const float* __restrict__ h, const float* __restrict__ fcW,
    const float* __restrict__ fcb, float* __restrict__ out, int N)
{
    __shared__ float WF[128 * 64];
    int tid = threadIdx.x;
    #pragma unroll
    for (int it = 0; it < 8; ++it) {
        int idx4 = (it * 256 + tid) * 4;
        *(float4*)&WF[idx4] = *(const float4*)&fcW[idx4];
    }
    __syncthreads();

    int j = tid & 63;
    int sub = tid >> 6;
    #pragma unroll
    for (int g = 0; g < 8; ++g) {
        int n = blockIdx.x * 32 + g * 4 + sub;
        if (n < N) {
            const float* hr = &h[(size_t)n * 128];
            float a = 0.f;
            #pragma unroll 4
            for (int kk = 0; kk < 32; ++kk) {
                float4 hv = *(const float4*)&hr[kk * 4];
                a += hv.x * WF[(kk * 4 + 0) * 64 + j];
                a += hv.y * WF[(kk * 4 + 1) * 64 + j];
                a += hv.z * WF[(kk * 4 + 2) * 64 + j];
                a += hv.w * WF[(kk * 4 + 3) * 64 + j];
            }
            out[(size_t)n * 64 + j] = a + fcb[j];
        }
    }
}

// ---------------------------------------------------------------------------
extern "C" void kernel_launch(void* const* d_in, const int* in_sizes, int n_in,
                              void* d_out, int out_size, void* d_ws, size_t ws_size,
                              hipStream_t stream)
{
    const float* features = (const float*)d_in[0];
    const int*   src0 = (const int*)d_in[1];
    const int*   dst0 = (const int*)d_in[2];
    const int*   types1 = (const int*)d_in[3];
    const int*   src1 = (const int*)d_in[4];
    const int*   dst1 = (const int*)d_in[5];
    const int*   types2 = (const int*)d_in[6];
    const int*   src2 = (const int*)d_in[7];
    const int*   dst2 = (const int*)d_in[8];
    const int*   types3 = (const int*)d_in[9];
    const float* convW = (const float*)d_in[10];
    const float* convb = (const float*)d_in[11];
    const float* fcW   = (const float*)d_in[12];
    const float* fcb   = (const float*)d_in[13];

    int E0 = in_sizes[1], N1 = in_sizes[3];
    int E1 = in_sizes[4], N2 = in_sizes[6];
    int E2 = in_sizes[7], N3 = in_sizes[9];
    int maxN = N1 > N2 ? N1 : N2; if (N3 > maxN) maxN = N3;

    // workspace layout
    char* ws = (char*)d_ws;
    size_t woff = 0;
    auto alloc = [&](size_t bytes) -> void* {
        void* p = ws + woff;
        woff = (woff + bytes + 255) & ~(size_t)255;
        return p;
    };
    float*    bufA  = (float*)alloc((size_t)maxN * 128 * 4);   // agg
    float*    bufB  = (float*)alloc((size_t)maxN * 128 * 4);   // h
    uint32_t* deg   = (uint32_t*)alloc((size_t)maxN * 4);
    int*      order = (int*)alloc((size_t)maxN * 4);
    uint32_t* cnt   = (uint32_t*)alloc(8 * 4);
    int*      boff  = (int*)alloc(9 * 4);
    uint32_t* cur   = (uint32_t*)alloc(8 * 4);
    (void)ws_size; (void)n_in; (void)out_size;

    // fold-in keys (host-side threefry): fold_in(key(42), i)
    uint32_t fk1a, fk1b, fk2a, fk2b;
    tf2x32(0u, 42u, 0u, 1u, &fk1a, &fk1b);
    tf2x32(0u, 42u, 0u, 2u, &fk2a, &fk2b);

    struct Layer {
        const float* hin; const int* src; const int* dst; const int* types;
        int E; int nout; int act; int drop; uint32_t fk0, fk1; float* hout;
    };
    Layer layers[3] = {
        { features, src0, dst0, types1, E0, N1, 1, 1, fk1a, fk1b, bufB },
        { bufB,     src1, dst1, types2, E1, N2, 1, 1, fk2a, fk2b, bufB },
        { bufB,     src2, dst2, types3, E2, N3, 0, 0, 0u, 0u,     bufB },
    };

    for (int L = 0; L < 3; ++L) {
        const Layer& ly = layers[L];
        hipMemsetAsync(bufA, 0, (size_t)ly.nout * 128 * 4, stream);
        hipMemsetAsync(deg, 0, (size_t)ly.nout * 4, stream);
        hipMemsetAsync(cnt, 0, 8 * 4, stream);

        long long sthreads = (long long)ly.E * 32;
        int sblocks = (int)((sthreads + 255) / 256);
        scatter_add_kernel<<<sblocks, 256, 0, stream>>>(ly.hin, ly.src, ly.dst, bufA, deg, ly.E);

        int nblk = (ly.nout + 255) / 256;
        count_types_kernel<<<nblk, 256, 0, stream>>>(ly.types, cnt, ly.nout);
        scan_types_kernel<<<1, 64, 0, stream>>>(cnt, boff, cur);
        fill_order_kernel<<<nblk, 256, 0, stream>>>(ly.types, cur, order, ly.nout);

        dim3 ggrid((ly.nout + 63) / 64, 8);
        type_gemm_kernel<<<ggrid, 256, 0, stream>>>(
            bufA, deg, order, boff, convW, convb, ly.hout,
            ly.act, ly.drop, ly.fk0, ly.fk1, (uint32_t)ly.nout * 64u);
    }

    fc_kernel<<<(N3 + 31) / 32, 256, 0, stream>>>(bufB, fcW, fcb, (float*)d_out, N3);
}

// Round 3
// 1046.239 us; speedup vs baseline: 7.6645x; 7.6645x over previous
//
#include <hip/hip_runtime.h>
#include <cstdint>
#include <cstddef>

// ---------------------------------------------------------------------------
// JAX threefry2x32 reproduction (20 rounds), host + device.
// fold_in(key(42), i) = threefry((0,42),(0,i))
// partitionable 32-bit random_bits: bits = o0 ^ o1 (XOR-fold)   [validated r2]
// uniform: u = bitcast((bits>>9)|0x3f800000) - 1.0f ; keep iff u < 0.9f
// ---------------------------------------------------------------------------
__host__ __device__ inline void tf2x32(uint32_t k0, uint32_t k1,
                                       uint32_t x0, uint32_t x1,
                                       uint32_t* o0, uint32_t* o1)
{
    uint32_t ks2 = k0 ^ k1 ^ 0x1BD11BDAu;
    x0 += k0; x1 += k1;
#define TF_R(r) do { x0 += x1; x1 = (x1 << (r)) | (x1 >> (32 - (r))); x1 ^= x0; } while (0)
    TF_R(13); TF_R(15); TF_R(26); TF_R(6);
    x0 += k1;  x1 += ks2 + 1u;
    TF_R(17); TF_R(29); TF_R(16); TF_R(24);
    x0 += ks2; x1 += k0 + 2u;
    TF_R(13); TF_R(15); TF_R(26); TF_R(6);
    x0 += k0;  x1 += k1 + 3u;
    TF_R(17); TF_R(29); TF_R(16); TF_R(24);
    x0 += k1;  x1 += ks2 + 4u;
    TF_R(13); TF_R(15); TF_R(26); TF_R(6);
    x0 += ks2; x1 += k0 + 5u;
#undef TF_R
    *o0 = x0; *o1 = x1;
}

__device__ inline float drop_scale(uint32_t fk0, uint32_t fk1, uint32_t idx)
{
    uint32_t o0, o1;
    tf2x32(fk0, fk1, 0u, idx, &o0, &o1);
    uint32_t bits = o0 ^ o1;         // XOR-fold (validated: absmax 9.8e-4)
    float u = __uint_as_float((bits >> 9) | 0x3f800000u) - 1.0f;
    return (u < 0.9f) ? (1.0f / 0.9f) : 0.0f;
}

// ---------------------------------------------------------------------------
// CSR build: deg histogram -> 3-kernel scan -> atomic fill of edge list
// ---------------------------------------------------------------------------
__global__ __launch_bounds__(256) void hist_dst_kernel(
    const int* __restrict__ dst, uint32_t* __restrict__ deg, int E)
{
    int e = blockIdx.x * 256 + threadIdx.x;
    if (e < E) atomicAdd(&deg[dst[e]], 1u);
}

// pass1: per-block (1024 elems) sums
__global__ __launch_bounds__(256) void scan_pass1(
    const uint32_t* __restrict__ v, uint32_t* __restrict__ bsum, int n)
{
    __shared__ uint32_t sd[256];
    int tid = threadIdx.x;
    int base = blockIdx.x * 1024 + tid * 4;
    uint32_t s = 0;
    #pragma unroll
    for (int i = 0; i < 4; ++i) { int idx = base + i; if (idx < n) s += v[idx]; }
    sd[tid] = s; __syncthreads();
    #pragma unroll
    for (int off = 128; off > 0; off >>= 1) {
        if (tid < off) sd[tid] += sd[tid + off];
        __syncthreads();
    }
    if (tid == 0) bsum[blockIdx.x] = sd[0];
}

// pass2: serial exclusive scan of block sums (nb <= ~200), writes rowptr[n]=total
__global__ void scan_pass2(uint32_t* __restrict__ bsum, int nb,
                           uint32_t* __restrict__ rowptr, int n)
{
    if (threadIdx.x == 0) {
        uint32_t a = 0;
        for (int i = 0; i < nb; ++i) { uint32_t t = bsum[i]; bsum[i] = a; a += t; }
        rowptr[n] = a;
    }
}

// pass3: local exclusive scan + block offset -> rowptr, cur
__global__ __launch_bounds__(256) void scan_pass3(
    const uint32_t* __restrict__ v, const uint32_t* __restrict__ bsum,
    uint32_t* __restrict__ rowptr, uint32_t* __restrict__ cur, int n)
{
    __shared__ uint32_t sd[256];
    int tid = threadIdx.x;
    int base = blockIdx.x * 1024 + tid * 4;
    uint32_t x[4]; uint32_t s = 0;
    #pragma unroll
    for (int i = 0; i < 4; ++i) {
        int idx = base + i;
        x[i] = (idx < n) ? v[idx] : 0u;
        s += x[i];
    }
    sd[tid] = s; __syncthreads();
    uint32_t inc = s;
    #pragma unroll
    for (int off = 1; off < 256; off <<= 1) {
        uint32_t y = (tid >= off) ? sd[tid - off] : 0u;
        __syncthreads();
        inc += y; sd[tid] = inc;
        __syncthreads();
    }
    uint32_t run = bsum[blockIdx.x] + inc - s;
    #pragma unroll
    for (int i = 0; i < 4; ++i) {
        int idx = base + i;
        if (idx < n) { rowptr[idx] = run; cur[idx] = run; run += x[i]; }
    }
}

__global__ __launch_bounds__(256) void csr_fill_kernel(
    const int* __restrict__ src, const int* __restrict__ dst,
    uint32_t* __restrict__ cur, int* __restrict__ elist, int E)
{
    int e = blockIdx.x * 256 + threadIdx.x;
    if (e < E) {
        uint32_t p = atomicAdd(&cur[dst[e]], 1u);
        elist[p] = src[e];
    }
}

// ---------------------------------------------------------------------------
// Gather-aggregate: one wave per dst node; lane owns 2 feats (float2).
// Writes normalized agg row once. No atomics, no pre-zeroing.
// ---------------------------------------------------------------------------
__global__ __launch_bounds__(256) void aggregate_kernel(
    const float* __restrict__ h, const uint32_t* __restrict__ rowptr,
    const int* __restrict__ elist, float* __restrict__ agg, int nout)
{
    int n = blockIdx.x * 4 + (threadIdx.x >> 6);
    if (n >= nout) return;
    int lane = threadIdx.x & 63;
    uint32_t beg = rowptr[n], end = rowptr[n + 1];
    const float* hl = h + (lane << 1);
    float ax = 0.f, ay = 0.f;
    uint32_t e = beg;
    for (; e + 2 <= end; e += 2) {
        int s0 = elist[e], s1 = elist[e + 1];
        float2 v0 = *(const float2*)(hl + (size_t)s0 * 128);
        float2 v1 = *(const float2*)(hl + (size_t)s1 * 128);
        ax += v0.x + v1.x; ay += v0.y + v1.y;
    }
    if (e < end) {
        int s0 = elist[e];
        float2 v0 = *(const float2*)(hl + (size_t)s0 * 128);
        ax += v0.x; ay += v0.y;
    }
    float sc = 1.0f / fmaxf((float)(end - beg), 1.0f);
    *(float2*)&agg[(size_t)n * 128 + (lane << 1)] = make_float2(ax * sc, ay * sc);
}

// ---------------------------------------------------------------------------
// Type bucketing (block-local histograms to cut 8-counter contention)
// ---------------------------------------------------------------------------
__global__ __launch_bounds__(256) void count_types_kernel(
    const int* __restrict__ types, uint32_t* __restrict__ cnt, int n)
{
    __shared__ uint32_t lh[8];
    int tid = threadIdx.x;
    if (tid < 8) lh[tid] = 0;
    __syncthreads();
    int i = blockIdx.x * 256 + tid;
    if (i < n) atomicAdd(&lh[types[i]], 1u);
    __syncthreads();
    if (tid < 8) atomicAdd(&cnt[tid], lh[tid]);
}

__global__ void scan_types_kernel(const uint32_t* __restrict__ cnt,
                                  int* __restrict__ off, uint32_t* __restrict__ cur)
{
    if (threadIdx.x == 0) {
        int a = 0;
        for (int t = 0; t < 8; ++t) { off[t] = a; cur[t] = (uint32_t)a; a += (int)cnt[t]; }
        off[8] = a;
    }
}

__global__ __launch_bounds__(256) void fill_order_kernel(
    const int* __restrict__ types, uint32_t* __restrict__ cur,
    int* __restrict__ order, int n)
{
    __shared__ uint32_t lh[8], lbase[8];
    int tid = threadIdx.x;
    if (tid < 8) lh[tid] = 0;
    __syncthreads();
    int i = blockIdx.x * 256 + tid;
    int t = -1; uint32_t r = 0;
    if (i < n) { t = types[i]; r = atomicAdd(&lh[t], 1u); }
    __syncthreads();
    if (tid < 8) lbase[tid] = atomicAdd(&cur[tid], lh[tid]);
    __syncthreads();
    if (i < n) order[lbase[t] + r] = i;
}

// ---------------------------------------------------------------------------
// Per-type GEMM: out[n] = [relu](agg[n] @ W[t] + b[t]) [* dropout]
// 512 threads, 128-node tile. tn=tid>>4 (4 rows each), tj=tid&15.
// LDS: WL 128xDOUT (no pad) + AL 128x132 (pad kills 4-way A conflict) + ND.
// DOUT=128: 132KB LDS -> 8 waves/CU (2/SIMD). DOUT=64 (fc-fused final): 100KB.
// ---------------------------------------------------------------------------
template<int DOUT, bool RELU, bool DROP>
__global__ __launch_bounds__(512) void type_gemm_kernel(
    const float* __restrict__ agg, const int* __restrict__ order,
    const int* __restrict__ off, const float* __restrict__ W8,
    const float* __restrict__ b8, float* __restrict__ hout,
    uint32_t fk0, uint32_t fk1)
{
    __shared__ float WL[128 * DOUT];
    __shared__ float AL[128 * 132];
    __shared__ int   ND[128];

    int t = blockIdx.y;
    int b0 = off[t] + blockIdx.x * 128;
    int bend = off[t + 1];
    if (b0 >= bend) return;
    int m = bend - b0; if (m > 128) m = 128;
    int tid = threadIdx.x;

    if (tid < 128) ND[tid] = (tid < m) ? order[b0 + tid] : -1;

    // stage W[t]
    const float* Wt = W8 + (size_t)t * (128 * DOUT);
    constexpr int WIT = (128 * DOUT / 4) / 512;
    #pragma unroll
    for (int it = 0; it < WIT; ++it) {
        int idx4 = (it * 512 + tid) * 4;
        int row = idx4 / DOUT, col = idx4 % DOUT;
        *(float4*)&WL[row * DOUT + col] = *(const float4*)&Wt[idx4];
    }
    __syncthreads();   // ND ready (and WL in flight rules: writes done at sync)

    // stage A (128 rows x 128 cols)
    #pragma unroll
    for (int it = 0; it < 8; ++it) {
        int f4 = (it * 512 + tid) * 4;
        int i = f4 >> 7, k = f4 & 127;
        float4 v = make_float4(0.f, 0.f, 0.f, 0.f);
        int nd = ND[i];
        if (nd >= 0) v = *(const float4*)&agg[(size_t)nd * 128 + k];
        *(float4*)&AL[i * 132 + k] = v;
    }
    __syncthreads();

    int tn = tid >> 4, tj = tid & 15;
    constexpr int NQ = DOUT / 16;          // 8 or 4
    float acc[4][NQ];
    #pragma unroll
    for (int a = 0; a < 4; ++a)
        #pragma unroll
        for (int b = 0; b < NQ; ++b) acc[a][b] = 0.f;

    const float* A0 = &AL[(tn * 4) * 132];
    #pragma unroll 2
    for (int k = 0; k < 128; ++k) {
        float av0 = A0[k], av1 = A0[132 + k], av2 = A0[264 + k], av3 = A0[396 + k];
        #pragma unroll
        for (int g = 0; g < DOUT / 64; ++g) {
            float4 w = *(const float4*)&WL[k * DOUT + g * 64 + tj * 4];
            float wv[4] = { w.x, w.y, w.z, w.w };
            #pragma unroll
            for (int q = 0; q < 4; ++q) {
                acc[0][g * 4 + q] += av0 * wv[q];
                acc[1][g * 4 + q] += av1 * wv[q];
                acc[2][g * 4 + q] += av2 * wv[q];
                acc[3][g * 4 + q] += av3 * wv[q];
            }
        }
    }

    const float* bptr = b8 + (size_t)t * DOUT;
    #pragma unroll
    for (int mi = 0; mi < 4; ++mi) {
        int nd = ND[tn * 4 + mi];
        if (nd < 0) continue;
        #pragma unroll
        for (int g = 0; g < DOUT / 64; ++g) {
            float o[4];
            #pragma unroll
            for (int q = 0; q < 4; ++q) {
                int j = g * 64 + tj * 4 + q;
                float v = acc[mi][g * 4 + q] + bptr[j];
                if (RELU) v = fmaxf(v, 0.f);
                if (DROP) v *= drop_scale(fk0, fk1, (uint32_t)nd * 128u + (uint32_t)j);
                o[q] = v;
            }
            *(float4*)&hout[(size_t)nd * DOUT + g * 64 + tj * 4] =
                make_float4(o[0], o[1], o[2], o[3]);
        }
    }
}

// ---------------------------------------------------------------------------
// Precompute fc-fused weights: Wf[t] = W[t] @ fcW (128x64), bf[t] = b[t]@fcW + fcb
// ---------------------------------------------------------------------------
__global__ __launch_bounds__(256) void fuse_fc_kernel(
    const float* __restrict__ convW, const float* __restrict__ convb,
    const float* __restrict__ fcW, const float* __restrict__ fcb,
    float* __restrict__ Wf, float* __restrict__ bf)
{
    __shared__ float F[128 * 64];
    int t = blockIdx.x, tid = threadIdx.x;
    #pragma unroll
    for (int it = 0; it < 8; ++it) {
        int idx4 = (it * 256 + tid) * 4;
        *(float4*)&F[idx4] = *(const float4*)&fcW[idx4];
    }
    __syncthreads();

    int r = tid >> 1, cb = (tid & 1) * 32;
    const float* Wrow = convW + (size_t)t * 16384 + (size_t)r * 128;
    float acc[32];
    #pragma unroll
    for (int c = 0; c < 32; ++c) acc[c] = 0.f;
    for (int k = 0; k < 128; ++k) {
        float w = Wrow[k];
        #pragma unroll
        for (int c = 0; c < 32; ++c) acc[c] += w * F[k * 64 + cb + c];
    }
    float* outp = Wf + (size_t)t * 8192 + (size_t)r * 64 + cb;
    #pragma unroll
    for (int c = 0; c < 32; ++c) outp[c] = acc[c];

    if (tid < 64) {
        float a = fcb[tid];
        const float* bt = convb + (size_t)t * 128;
        for (int k = 0; k < 128; ++k) a += bt[k] * F[k * 64 + tid];
        bf[(size_t)t * 64 + tid] = a;
    }
}

// ---------------------------------------------------------------------------
extern "C" void kernel_launch(void* const* d_in, const int* in_sizes, int n_in,
                              void* d_out, int out_size, void* d_ws, size_t ws_size,
                              hipStream_t stream)
{
    const float* features = (const float*)d_in[0];
    const int*   src0 = (const int*)d_in[1];
    const int*   dst0 = (const int*)d_in[2];
    const int*   types1 = (const int*)d_in[3];
    const int*   src1 = (const int*)d_in[4];
    const int*   dst1 = (const int*)d_in[5];
    const int*   types2 = (const int*)d_in[6];
    const int*   src2 = (const int*)d_in[7];
    const int*   dst2 = (const int*)d_in[8];
    const int*   types3 = (const int*)d_in[9];
    const float* convW = (const float*)d_in[10];
    const float* convb = (const float*)d_in[11];
    const float* fcW   = (const float*)d_in[12];
    const float* fcb   = (const float*)d_in[13];

    int E0 = in_sizes[1], N1 = in_sizes[3];
    int E1 = in_sizes[4], N2 = in_sizes[6];
    int E2 = in_sizes[7], N3 = in_sizes[9];
    int maxN = N1 > N2 ? N1 : N2; if (N3 > maxN) maxN = N3;
    int maxE = E0 > E1 ? E0 : E1; if (E2 > maxE) maxE = E2;

    char* ws = (char*)d_ws;
    size_t woff = 0;
    auto alloc = [&](size_t bytes) -> void* {
        void* p = ws + woff;
        woff = (woff + bytes + 255) & ~(size_t)255;
        return p;
    };
    float*    bufA   = (float*)alloc((size_t)maxN * 128 * 4);     // agg
    float*    bufB   = (float*)alloc((size_t)maxN * 128 * 4);     // h
    uint32_t* deg    = (uint32_t*)alloc((size_t)maxN * 4);
    uint32_t* rowptr = (uint32_t*)alloc((size_t)(maxN + 1) * 4);
    uint32_t* cur    = (uint32_t*)alloc((size_t)maxN * 4);
    int*      elist  = (int*)alloc((size_t)maxE * 4);
    int*      order  = (int*)alloc((size_t)maxN * 4);
    uint32_t* bsum   = (uint32_t*)alloc(1024 * 4);
    uint32_t* tcnt   = (uint32_t*)alloc(8 * 4);
    int*      boff   = (int*)alloc(9 * 4);
    uint32_t* tcur   = (uint32_t*)alloc(8 * 4);
    float*    Wf     = (float*)alloc((size_t)8 * 128 * 64 * 4);
    float*    bf     = (float*)alloc((size_t)8 * 64 * 4);
    (void)ws_size; (void)n_in; (void)out_size;

    // fc-fused final weights (independent of layer data)
    fuse_fc_kernel<<<8, 256, 0, stream>>>(convW, convb, fcW, fcb, Wf, bf);

    uint32_t fk1a, fk1b, fk2a, fk2b;
    tf2x32(0u, 42u, 0u, 1u, &fk1a, &fk1b);
    tf2x32(0u, 42u, 0u, 2u, &fk2a, &fk2b);

    struct Layer {
        const float* hin; const int* src; const int* dst; const int* types;
        int E; int nout; uint32_t fk0, fk1;
    };
    Layer layers[3] = {
        { features, src0, dst0, types1, E0, N1, fk1a, fk1b },
        { bufB,     src1, dst1, types2, E1, N2, fk2a, fk2b },
        { bufB,     src2, dst2, types3, E2, N3, 0u, 0u },
    };

    for (int L = 0; L < 3; ++L) {
        const Layer& ly = layers[L];
        int N = ly.nout, E = ly.E;
        int nb = (N + 1023) / 1024;

        // --- CSR build ---
        hipMemsetAsync(deg, 0, (size_t)N * 4, stream);
        hist_dst_kernel<<<(E + 255) / 256, 256, 0, stream>>>(ly.dst, deg, E);
        scan_pass1<<<nb, 256, 0, stream>>>(deg, bsum, N);
        scan_pass2<<<1, 64, 0, stream>>>(bsum, nb, rowptr, N);
        scan_pass3<<<nb, 256, 0, stream>>>(deg, bsum, rowptr, cur, N);
        csr_fill_kernel<<<(E + 255) / 256, 256, 0, stream>>>(ly.src, ly.dst, cur, elist, E);

        // --- gather-aggregate (writes normalized agg, no atomics) ---
        aggregate_kernel<<<(N + 3) / 4, 256, 0, stream>>>(ly.hin, rowptr, elist, bufA, N);

        // --- type bucketing ---
        hipMemsetAsync(tcnt, 0, 8 * 4, stream);
        int nblk = (N + 255) / 256;
        count_types_kernel<<<nblk, 256, 0, stream>>>(ly.types, tcnt, N);
        scan_types_kernel<<<1, 64, 0, stream>>>(tcnt, boff, tcur);
        fill_order_kernel<<<nblk, 256, 0, stream>>>(ly.types, tcur, order, N);

        // --- per-type GEMM ---
        dim3 ggrid((N + 127) / 128, 8);
        if (L == 0) {
            type_gemm_kernel<128, true, true><<<ggrid, 512, 0, stream>>>(
                bufA, order, boff, convW, convb, bufB, ly.fk0, ly.fk1);
        } else if (L == 1) {
            type_gemm_kernel<128, true, true><<<ggrid, 512, 0, stream>>>(
                bufA, order, boff, convW, convb, bufB, ly.fk0, ly.fk1);
        } else {
            // final layer: fc folded in, writes d_out directly (50K x 64)
            type_gemm_kernel<64, false, false><<<ggrid, 512, 0, stream>>>(
                bufA, order, boff, Wf, bf, (float*)d_out, 0u, 0u);
        }
    }
}

// Round 4
// 991.421 us; speedup vs baseline: 8.0882x; 1.0553x over previous
//
#include <hip/hip_runtime.h>
#include <cstdint>
#include <cstddef>

// ---------------------------------------------------------------------------
// JAX threefry2x32 (20 rounds). fold_in(key(42), i) = threefry((0,42),(0,i))
// partitionable 32-bit random_bits: bits = o0 ^ o1 (XOR-fold)   [validated r2]
// uniform: u = bitcast((bits>>9)|0x3f800000) - 1.0f ; keep iff u < 0.9f
// ---------------------------------------------------------------------------
__host__ __device__ inline void tf2x32(uint32_t k0, uint32_t k1,
                                       uint32_t x0, uint32_t x1,
                                       uint32_t* o0, uint32_t* o1)
{
    uint32_t ks2 = k0 ^ k1 ^ 0x1BD11BDAu;
    x0 += k0; x1 += k1;
#define TF_R(r) do { x0 += x1; x1 = (x1 << (r)) | (x1 >> (32 - (r))); x1 ^= x0; } while (0)
    TF_R(13); TF_R(15); TF_R(26); TF_R(6);
    x0 += k1;  x1 += ks2 + 1u;
    TF_R(17); TF_R(29); TF_R(16); TF_R(24);
    x0 += ks2; x1 += k0 + 2u;
    TF_R(13); TF_R(15); TF_R(26); TF_R(6);
    x0 += k0;  x1 += k1 + 3u;
    TF_R(17); TF_R(29); TF_R(16); TF_R(24);
    x0 += k1;  x1 += ks2 + 4u;
    TF_R(13); TF_R(15); TF_R(26); TF_R(6);
    x0 += ks2; x1 += k0 + 5u;
#undef TF_R
    *o0 = x0; *o1 = x1;
}

__device__ inline float drop_scale(uint32_t fk0, uint32_t fk1, uint32_t idx)
{
    uint32_t o0, o1;
    tf2x32(fk0, fk1, 0u, idx, &o0, &o1);
    uint32_t bits = o0 ^ o1;
    float u = __uint_as_float((bits >> 9) | 0x3f800000u) - 1.0f;
    return (u < 0.9f) ? (1.0f / 0.9f) : 0.0f;
}

// bf16 helpers (round-to-nearest-even)
__device__ inline ushort bf16_rn(float f)
{
    uint32_t u = __float_as_uint(f);
    u += 0x7fffu + ((u >> 16) & 1u);
    return (ushort)(u >> 16);
}
__device__ inline float bf16_f(ushort h) { return __uint_as_float(((uint32_t)h) << 16); }

typedef __attribute__((ext_vector_type(8))) short bf16x8;
typedef __attribute__((ext_vector_type(4))) float f32x4;

// ---------------------------------------------------------------------------
// CSR build: deg histogram -> 3-kernel scan -> atomic fill of edge list
// ---------------------------------------------------------------------------
__global__ __launch_bounds__(256) void hist_dst_kernel(
    const int* __restrict__ dst, uint32_t* __restrict__ deg, int E)
{
    int e = blockIdx.x * 256 + threadIdx.x;
    if (e < E) atomicAdd(&deg[dst[e]], 1u);
}

__global__ __launch_bounds__(256) void scan_pass1(
    const uint32_t* __restrict__ v, uint32_t* __restrict__ bsum, int n)
{
    __shared__ uint32_t sd[256];
    int tid = threadIdx.x;
    int base = blockIdx.x * 1024 + tid * 4;
    uint32_t s = 0;
    #pragma unroll
    for (int i = 0; i < 4; ++i) { int idx = base + i; if (idx < n) s += v[idx]; }
    sd[tid] = s; __syncthreads();
    #pragma unroll
    for (int off = 128; off > 0; off >>= 1) {
        if (tid < off) sd[tid] += sd[tid + off];
        __syncthreads();
    }
    if (tid == 0) bsum[blockIdx.x] = sd[0];
}

__global__ void scan_pass2(uint32_t* __restrict__ bsum, int nb,
                           uint32_t* __restrict__ rowptr, int n)
{
    if (threadIdx.x == 0) {
        uint32_t a = 0;
        for (int i = 0; i < nb; ++i) { uint32_t t = bsum[i]; bsum[i] = a; a += t; }
        rowptr[n] = a;
    }
}

__global__ __launch_bounds__(256) void scan_pass3(
    const uint32_t* __restrict__ v, const uint32_t* __restrict__ bsum,
    uint32_t* __restrict__ rowptr, uint32_t* __restrict__ cur, int n)
{
    __shared__ uint32_t sd[256];
    int tid = threadIdx.x;
    int base = blockIdx.x * 1024 + tid * 4;
    uint32_t x[4]; uint32_t s = 0;
    #pragma unroll
    for (int i = 0; i < 4; ++i) {
        int idx = base + i;
        x[i] = (idx < n) ? v[idx] : 0u;
        s += x[i];
    }
    sd[tid] = s; __syncthreads();
    uint32_t inc = s;
    #pragma unroll
    for (int off = 1; off < 256; off <<= 1) {
        uint32_t y = (tid >= off) ? sd[tid - off] : 0u;
        __syncthreads();
        inc += y; sd[tid] = inc;
        __syncthreads();
    }
    uint32_t run = bsum[blockIdx.x] + inc - s;
    #pragma unroll
    for (int i = 0; i < 4; ++i) {
        int idx = base + i;
        if (idx < n) { rowptr[idx] = run; cur[idx] = run; run += x[i]; }
    }
}

__global__ __launch_bounds__(256) void csr_fill_kernel(
    const int* __restrict__ src, const int* __restrict__ dst,
    uint32_t* __restrict__ cur, int* __restrict__ elist, int E)
{
    int e = blockIdx.x * 256 + threadIdx.x;
    if (e < E) {
        uint32_t p = atomicAdd(&cur[dst[e]], 1u);
        elist[p] = src[e];
    }
}

// ---------------------------------------------------------------------------
// Gather-aggregate: one wave per dst node; lane owns 2 feats (float2).
// Writes normalized agg row as bf16 hi/lo pair (packed 2 per uint, linear).
// ---------------------------------------------------------------------------
__global__ __launch_bounds__(256) void aggregate_kernel(
    const float* __restrict__ h, const uint32_t* __restrict__ rowptr,
    const int* __restrict__ elist, uint32_t* __restrict__ agghi,
    uint32_t* __restrict__ agglo, int nout)
{
    int n = blockIdx.x * 4 + (threadIdx.x >> 6);
    if (n >= nout) return;
    int lane = threadIdx.x & 63;
    uint32_t beg = rowptr[n], end = rowptr[n + 1];
    const float* hl = h + (lane << 1);
    float ax = 0.f, ay = 0.f;
    uint32_t e = beg;
    for (; e + 2 <= end; e += 2) {
        int s0 = elist[e], s1 = elist[e + 1];
        float2 v0 = *(const float2*)(hl + (size_t)s0 * 128);
        float2 v1 = *(const float2*)(hl + (size_t)s1 * 128);
        ax += v0.x + v1.x; ay += v0.y + v1.y;
    }
    if (e < end) {
        int s0 = elist[e];
        float2 v0 = *(const float2*)(hl + (size_t)s0 * 128);
        ax += v0.x; ay += v0.y;
    }
    float sc = 1.0f / fmaxf((float)(end - beg), 1.0f);
    ax *= sc; ay *= sc;
    ushort hx = bf16_rn(ax); ushort lx = bf16_rn(ax - bf16_f(hx));
    ushort hy = bf16_rn(ay); ushort ly = bf16_rn(ay - bf16_f(hy));
    agghi[(size_t)n * 64 + lane] = (uint32_t)hx | ((uint32_t)hy << 16);
    agglo[(size_t)n * 64 + lane] = (uint32_t)lx | ((uint32_t)ly << 16);
}

// ---------------------------------------------------------------------------
// Type bucketing
// ---------------------------------------------------------------------------
__global__ __launch_bounds__(256) void count_types_kernel(
    const int* __restrict__ types, uint32_t* __restrict__ cnt, int n)
{
    __shared__ uint32_t lh[8];
    int tid = threadIdx.x;
    if (tid < 8) lh[tid] = 0;
    __syncthreads();
    int i = blockIdx.x * 256 + tid;
    if (i < n) atomicAdd(&lh[types[i]], 1u);
    __syncthreads();
    if (tid < 8) atomicAdd(&cnt[tid], lh[tid]);
}

__global__ void scan_types_kernel(const uint32_t* __restrict__ cnt,
                                  int* __restrict__ off, uint32_t* __restrict__ cur)
{
    if (threadIdx.x == 0) {
        int a = 0;
        for (int t = 0; t < 8; ++t) { off[t] = a; cur[t] = (uint32_t)a; a += (int)cnt[t]; }
        off[8] = a;
    }
}

__global__ __launch_bounds__(256) void fill_order_kernel(
    const int* __restrict__ types, uint32_t* __restrict__ cur,
    int* __restrict__ order, int n)
{
    __shared__ uint32_t lh[8], lbase[8];
    int tid = threadIdx.x;
    if (tid < 8) lh[tid] = 0;
    __syncthreads();
    int i = blockIdx.x * 256 + tid;
    int t = -1; uint32_t r = 0;
    if (i < n) { t = types[i]; r = atomicAdd(&lh[t], 1u); }
    __syncthreads();
    if (tid < 8) lbase[tid] = atomicAdd(&cur[tid], lh[tid]);
    __syncthreads();
    if (i < n) order[lbase[t] + r] = i;
}

// ---------------------------------------------------------------------------
// Weight prep: src f32 [8][128][C] (k-major) -> dst bf16 hi/lo [8][C][128]
// transposed + XOR-swizzled: chunk' = (k>>3) ^ (c&15). One-time, tiny.
// ---------------------------------------------------------------------------
__global__ __launch_bounds__(256) void prep_wt_kernel(
    const float* __restrict__ src8, ushort* __restrict__ dsthi,
    ushort* __restrict__ dstlo, int C)
{
    int t = blockIdx.x;
    const float* S = src8 + (size_t)t * 128 * C;
    ushort* DH = dsthi + (size_t)t * C * 128;
    ushort* DL = dstlo + (size_t)t * C * 128;
    for (int idx = threadIdx.x; idx < 128 * C; idx += 256) {
        int k = idx / C, c = idx % C;   // coalesced read over c
        float v = S[(size_t)k * C + c];
        ushort hi = bf16_rn(v);
        ushort lo = bf16_rn(v - bf16_f(hi));
        int pos = c * 128 + ((((k >> 3) ^ (c & 15)) << 3) | (k & 7));
        DH[pos] = hi; DL[pos] = lo;
    }
}

// ---------------------------------------------------------------------------
// MFMA GEMM (split-bf16): out[n] = [relu](agg[n] @ W[t] + b[t]) [* dropout]
// 512 thr = 8 waves; tile M=128 x N=DOUT, K=128. Wave = 16 rows x DOUT cols.
// mfma_f32_16x16x32_bf16; 3-term split (hi*hi + hi*lo + lo*hi).
// Frag maps: A lane: row=l&15, k=(l>>4)*8+j ; B lane: col=l&15, k=(l>>4)*8+j ;
// C/D: col=lane&15, row=(lane>>4)*4+reg   [m89-verified]
// LDS XOR-swizzle chunk ^ (row&15) -> 2-way max (free).
// ---------------------------------------------------------------------------
template<int DOUT, bool RELU, bool DROP>
__global__ __launch_bounds__(512) void mfma_gemm_kernel(
    const uint32_t* __restrict__ agghi, const uint32_t* __restrict__ agglo,
    const int* __restrict__ order, const int* __restrict__ off,
    const ushort* __restrict__ WThi, const ushort* __restrict__ WTlo,
    const float* __restrict__ bias8, float* __restrict__ hout,
    uint32_t fk0, uint32_t fk1)
{
    __shared__ ushort AH[128 * 128];
    __shared__ ushort AL[128 * 128];
    __shared__ ushort WH[DOUT * 128];
    __shared__ ushort WL[DOUT * 128];
    __shared__ int ND[128];

    int t = blockIdx.y;
    int b0 = off[t] + blockIdx.x * 128;
    int bend = off[t + 1];
    if (b0 >= bend) return;
    int m = bend - b0; if (m > 128) m = 128;
    int tid = threadIdx.x;

    if (tid < 128) ND[tid] = (tid < m) ? order[b0 + tid] : -1;
    __syncthreads();

    // stage W (pre-transposed, pre-swizzled in global -> straight copy)
    {
        const float4* sh = (const float4*)(WThi + (size_t)t * DOUT * 128);
        const float4* sl = (const float4*)(WTlo + (size_t)t * DOUT * 128);
        float4* dh = (float4*)WH; float4* dl = (float4*)WL;
        #pragma unroll
        for (int it = 0; it < DOUT * 16 / 512; ++it) {
            int c = it * 512 + tid;
            dh[c] = sh[c]; dl[c] = sl[c];
        }
    }
    // stage A: gather rows via ND, swizzle chunk by tile-local (row&15)
    {
        const float4* gh = (const float4*)agghi;
        const float4* gl = (const float4*)agglo;
        float4* dh = (float4*)AH; float4* dl = (float4*)AL;
        #pragma unroll
        for (int it = 0; it < 4; ++it) {
            int g = it * 512 + tid;        // 2048 chunks
            int row = g >> 4, ch = g & 15;
            int nd = ND[row];
            float4 vh = make_float4(0.f, 0.f, 0.f, 0.f);
            float4 vl = make_float4(0.f, 0.f, 0.f, 0.f);
            if (nd >= 0) {
                vh = gh[(size_t)nd * 16 + ch];
                vl = gl[(size_t)nd * 16 + ch];
            }
            int dch = ch ^ (row & 15);
            dh[row * 16 + dch] = vh;
            dl[row * 16 + dch] = vl;
        }
    }
    __syncthreads();

    int wid = tid >> 6, lane = tid & 63;
    int r15 = lane & 15, q = lane >> 4;
    constexpr int NF = DOUT / 16;
    f32x4 acc[NF];
    #pragma unroll
    for (int i = 0; i < NF; ++i) acc[i] = (f32x4){0.f, 0.f, 0.f, 0.f};

    int arow = wid * 16 + r15;
    const bf16x8* AHp = (const bf16x8*)AH;
    const bf16x8* ALp = (const bf16x8*)AL;
    const bf16x8* WHp = (const bf16x8*)WH;
    const bf16x8* WLp = (const bf16x8*)WL;

    #pragma unroll
    for (int ks = 0; ks < 4; ++ks) {
        int sch = (q + ks * 4) ^ r15;
        bf16x8 ah = AHp[arow * 16 + sch];
        bf16x8 al = ALp[arow * 16 + sch];
        #pragma unroll
        for (int nf = 0; nf < NF; ++nf) {
            int col = nf * 16 + r15;
            bf16x8 bh = WHp[col * 16 + sch];
            bf16x8 bl = WLp[col * 16 + sch];
            acc[nf] = __builtin_amdgcn_mfma_f32_16x16x32_bf16(ah, bh, acc[nf], 0, 0, 0);
            acc[nf] = __builtin_amdgcn_mfma_f32_16x16x32_bf16(ah, bl, acc[nf], 0, 0, 0);
            acc[nf] = __builtin_amdgcn_mfma_f32_16x16x32_bf16(al, bh, acc[nf], 0, 0, 0);
        }
    }

    // epilogue: C/D row = wid*16 + q*4 + r, col = nf*16 + r15
    const float* bptr = bias8 + (size_t)t * DOUT;
    #pragma unroll
    for (int nf = 0; nf < NF; ++nf) {
        int col = nf * 16 + r15;
        float bv = bptr[col];
        #pragma unroll
        for (int r = 0; r < 4; ++r) {
            int rl = wid * 16 + q * 4 + r;
            int nd = ND[rl];
            if (nd < 0) continue;
            float v = acc[nf][r] + bv;
            if (RELU) v = fmaxf(v, 0.f);
            if (DROP) v *= drop_scale(fk0, fk1, (uint32_t)nd * 128u + (uint32_t)col);
            hout[(size_t)nd * DOUT + col] = v;
        }
    }
}

// ---------------------------------------------------------------------------
// fc fusion: Wf[t] = W[t] @ fcW (128x64 f32), bf[t] = b[t] @ fcW + fcb
// ---------------------------------------------------------------------------
__global__ __launch_bounds__(256) void fuse_fc_kernel(
    const float* __restrict__ convW, const float* __restrict__ convb,
    const float* __restrict__ fcW, const float* __restrict__ fcb,
    float* __restrict__ Wf, float* __restrict__ bf)
{
    __shared__ float F[128 * 64];
    int t = blockIdx.x, tid = threadIdx.x;
    #pragma unroll
    for (int it = 0; it < 8; ++it) {
        int idx4 = (it * 256 + tid) * 4;
        *(float4*)&F[idx4] = *(const float4*)&fcW[idx4];
    }
    __syncthreads();

    int r = tid >> 1, cb = (tid & 1) * 32;
    const float* Wrow = convW + (size_t)t * 16384 + (size_t)r * 128;
    float acc[32];
    #pragma unroll
    for (int c = 0; c < 32; ++c) acc[c] = 0.f;
    for (int k = 0; k < 128; ++k) {
        float w = Wrow[k];
        #pragma unroll
        for (int c = 0; c < 32; ++c) acc[c] += w * F[k * 64 + cb + c];
    }
    float* outp = Wf + (size_t)t * 8192 + (size_t)r * 64 + cb;
    #pragma unroll
    for (int c = 0; c < 32; ++c) outp[c] = acc[c];

    if (tid < 64) {
        float a = fcb[tid];
        const float* bt = convb + (size_t)t * 128;
        for (int k = 0; k < 128; ++k) a += bt[k] * F[k * 64 + tid];
        bf[(size_t)t * 64 + tid] = a;
    }
}

// ---------------------------------------------------------------------------
extern "C" void kernel_launch(void* const* d_in, const int* in_sizes, int n_in,
                              void* d_out, int out_size, void* d_ws, size_t ws_size,
                              hipStream_t stream)
{
    const float* features = (const float*)d_in[0];
    const int*   src0 = (const int*)d_in[1];
    const int*   dst0 = (const int*)d_in[2];
    const int*   types1 = (const int*)d_in[3];
    const int*   src1 = (const int*)d_in[4];
    const int*   dst1 = (const int*)d_in[5];
    const int*   types2 = (const int*)d_in[6];
    const int*   src2 = (const int*)d_in[7];
    const int*   dst2 = (const int*)d_in[8];
    const int*   types3 = (const int*)d_in[9];
    const float* convW = (const float*)d_in[10];
    const float* convb = (const float*)d_in[11];
    const float* fcW   = (const float*)d_in[12];
    const float* fcb   = (const float*)d_in[13];

    int E0 = in_sizes[1], N1 = in_sizes[3];
    int E1 = in_sizes[4], N2 = in_sizes[6];
    int E2 = in_sizes[7], N3 = in_sizes[9];
    int maxN = N1 > N2 ? N1 : N2; if (N3 > maxN) maxN = N3;
    int maxE = E0 > E1 ? E0 : E1; if (E2 > maxE) maxE = E2;

    char* ws = (char*)d_ws;
    size_t woff = 0;
    auto alloc = [&](size_t bytes) -> void* {
        void* p = ws + woff;
        woff = (woff + bytes + 255) & ~(size_t)255;
        return p;
    };
    uint32_t* aggHi  = (uint32_t*)alloc((size_t)maxN * 64 * 4);   // bf16x2 packed
    uint32_t* aggLo  = (uint32_t*)alloc((size_t)maxN * 64 * 4);
    float*    bufB   = (float*)alloc((size_t)maxN * 128 * 4);     // h (f32)
    uint32_t* deg    = (uint32_t*)alloc((size_t)maxN * 4);
    uint32_t* rowptr = (uint32_t*)alloc((size_t)(maxN + 1) * 4);
    uint32_t* cur    = (uint32_t*)alloc((size_t)maxN * 4);
    int*      elist  = (int*)alloc((size_t)maxE * 4);
    int*      order  = (int*)alloc((size_t)maxN * 4);
    uint32_t* bsum   = (uint32_t*)alloc(1024 * 4);
    uint32_t* tcnt   = (uint32_t*)alloc(8 * 4);
    int*      boff   = (int*)alloc(9 * 4);
    uint32_t* tcur   = (uint32_t*)alloc(8 * 4);
    float*    Wf     = (float*)alloc((size_t)8 * 128 * 64 * 4);
    float*    bf     = (float*)alloc((size_t)8 * 64 * 4);
    ushort*   WThi   = (ushort*)alloc((size_t)8 * 128 * 128 * 2);
    ushort*   WTlo   = (ushort*)alloc((size_t)8 * 128 * 128 * 2);
    ushort*   WfThi  = (ushort*)alloc((size_t)8 * 64 * 128 * 2);
    ushort*   WfTlo  = (ushort*)alloc((size_t)8 * 64 * 128 * 2);
    (void)ws_size; (void)n_in; (void)out_size;

    // one-time weight prep
    prep_wt_kernel<<<8, 256, 0, stream>>>(convW, WThi, WTlo, 128);
    fuse_fc_kernel<<<8, 256, 0, stream>>>(convW, convb, fcW, fcb, Wf, bf);
    prep_wt_kernel<<<8, 256, 0, stream>>>(Wf, WfThi, WfTlo, 64);

    uint32_t fk1a, fk1b, fk2a, fk2b;
    tf2x32(0u, 42u, 0u, 1u, &fk1a, &fk1b);
    tf2x32(0u, 42u, 0u, 2u, &fk2a, &fk2b);

    struct Layer {
        const float* hin; const int* src; const int* dst; const int* types;
        int E; int nout; uint32_t fk0, fk1;
    };
    Layer layers[3] = {
        { features, src0, dst0, types1, E0, N1, fk1a, fk1b },
        { bufB,     src1, dst1, types2, E1, N2, fk2a, fk2b },
        { bufB,     src2, dst2, types3, E2, N3, 0u, 0u },
    };

    for (int L = 0; L < 3; ++L) {
        const Layer& ly = layers[L];
        int N = ly.nout, E = ly.E;
        int nb = (N + 1023) / 1024;

        // --- CSR build ---
        hipMemsetAsync(deg, 0, (size_t)N * 4, stream);
        hist_dst_kernel<<<(E + 255) / 256, 256, 0, stream>>>(ly.dst, deg, E);
        scan_pass1<<<nb, 256, 0, stream>>>(deg, bsum, N);
        scan_pass2<<<1, 64, 0, stream>>>(bsum, nb, rowptr, N);
        scan_pass3<<<nb, 256, 0, stream>>>(deg, bsum, rowptr, cur, N);
        csr_fill_kernel<<<(E + 255) / 256, 256, 0, stream>>>(ly.src, ly.dst, cur, elist, E);

        // --- gather-aggregate -> bf16 hi/lo ---
        aggregate_kernel<<<(N + 3) / 4, 256, 0, stream>>>(ly.hin, rowptr, elist, aggHi, aggLo, N);

        // --- type bucketing ---
        hipMemsetAsync(tcnt, 0, 8 * 4, stream);
        int nblk = (N + 255) / 256;
        count_types_kernel<<<nblk, 256, 0, stream>>>(ly.types, tcnt, N);
        scan_types_kernel<<<1, 64, 0, stream>>>(tcnt, boff, tcur);
        fill_order_kernel<<<nblk, 256, 0, stream>>>(ly.types, tcur, order, N);

        // --- per-type split-bf16 MFMA GEMM ---
        dim3 ggrid((N + 127) / 128, 8);
        if (L == 0) {
            mfma_gemm_kernel<128, true, true><<<ggrid, 512, 0, stream>>>(
                aggHi, aggLo, order, boff, WThi, WTlo, convb, bufB, ly.fk0, ly.fk1);
        } else if (L == 1) {
            mfma_gemm_kernel<128, true, true><<<ggrid, 512, 0, stream>>>(
                aggHi, aggLo, order, boff, WThi, WTlo, convb, bufB, ly.fk0, ly.fk1);
        } else {
            mfma_gemm_kernel<64, false, false><<<ggrid, 512, 0, stream>>>(
                aggHi, aggLo, order, boff, WfThi, WfTlo, bf, (float*)d_out, 0u, 0u);
        }
    }
}

// Round 5
// 891.097 us; speedup vs baseline: 8.9989x; 1.1126x over previous
//
#include <hip/hip_runtime.h>
#include <cstdint>
#include <cstddef>

// ---------------------------------------------------------------------------
// JAX threefry2x32 (20 rounds). fold_in(key(42), i) = threefry((0,42),(0,i))
// partitionable 32-bit random_bits: bits = o0 ^ o1 (XOR-fold)   [validated r2]
// uniform: u = bitcast((bits>>9)|0x3f800000) - 1.0f ; keep iff u < 0.9f
// ---------------------------------------------------------------------------
__host__ __device__ inline void tf2x32(uint32_t k0, uint32_t k1,
                                       uint32_t x0, uint32_t x1,
                                       uint32_t* o0, uint32_t* o1)
{
    uint32_t ks2 = k0 ^ k1 ^ 0x1BD11BDAu;
    x0 += k0; x1 += k1;
#define TF_R(r) do { x0 += x1; x1 = (x1 << (r)) | (x1 >> (32 - (r))); x1 ^= x0; } while (0)
    TF_R(13); TF_R(15); TF_R(26); TF_R(6);
    x0 += k1;  x1 += ks2 + 1u;
    TF_R(17); TF_R(29); TF_R(16); TF_R(24);
    x0 += ks2; x1 += k0 + 2u;
    TF_R(13); TF_R(15); TF_R(26); TF_R(6);
    x0 += k0;  x1 += k1 + 3u;
    TF_R(17); TF_R(29); TF_R(16); TF_R(24);
    x0 += k1;  x1 += ks2 + 4u;
    TF_R(13); TF_R(15); TF_R(26); TF_R(6);
    x0 += ks2; x1 += k0 + 5u;
#undef TF_R
    *o0 = x0; *o1 = x1;
}

__device__ inline float drop_scale(uint32_t fk0, uint32_t fk1, uint32_t idx)
{
    uint32_t o0, o1;
    tf2x32(fk0, fk1, 0u, idx, &o0, &o1);
    uint32_t bits = o0 ^ o1;
    float u = __uint_as_float((bits >> 9) | 0x3f800000u) - 1.0f;
    return (u < 0.9f) ? (1.0f / 0.9f) : 0.0f;
}

// bf16 helpers (round-to-nearest-even)
__device__ inline ushort bf16_rn(float f)
{
    uint32_t u = __float_as_uint(f);
    u += 0x7fffu + ((u >> 16) & 1u);
    return (ushort)(u >> 16);
}
__device__ inline float bf16_f(ushort h) { return __uint_as_float(((uint32_t)h) << 16); }
__device__ inline uint32_t pack2bf(float a, float b)
{
    return (uint32_t)bf16_rn(a) | ((uint32_t)bf16_rn(b) << 16);
}
__device__ inline float bflo(uint32_t u) { return __uint_as_float(u << 16); }
__device__ inline float bfhi(uint32_t u) { return __uint_as_float(u & 0xffff0000u); }

typedef __attribute__((ext_vector_type(8))) short bf16x8;
typedef __attribute__((ext_vector_type(4))) float f32x4;

// ---------------------------------------------------------------------------
// features f32 -> packed bf16x2 (one-time per call, streaming)
// ---------------------------------------------------------------------------
__global__ __launch_bounds__(256) void fcvt_kernel(
    const float4* __restrict__ in, uint2* __restrict__ out, long long n4)
{
    long long stride = (long long)gridDim.x * 256;
    for (long long i = blockIdx.x * 256LL + threadIdx.x; i < n4; i += stride) {
        float4 v = in[i];
        out[i] = make_uint2(pack2bf(v.x, v.y), pack2bf(v.z, v.w));
    }
}

// ---------------------------------------------------------------------------
// Batched CSR build over all 3 layers (dst-only dependent)
// ---------------------------------------------------------------------------
__global__ __launch_bounds__(256) void hist3_kernel(
    const int* __restrict__ d0, const int* __restrict__ d1, const int* __restrict__ d2,
    int E0, int E1, int E2, uint32_t* __restrict__ deg, int o1, int o2)
{
    int e = blockIdx.x * 256 + threadIdx.x;
    if (e < E0) atomicAdd(&deg[d0[e]], 1u);
    else if (e < E0 + E1) atomicAdd(&deg[o1 + d1[e - E0]], 1u);
    else if (e < E0 + E1 + E2) atomicAdd(&deg[o2 + d2[e - E0 - E1]], 1u);
}

// pass1: per-block (1024 elems) sums; blockIdx.y = layer
__global__ __launch_bounds__(256) void scan1b_kernel(
    const uint32_t* __restrict__ deg3, uint32_t* __restrict__ bsum3,
    int n0, int n1, int n2, int no1, int no2)
{
    int L = blockIdx.y;
    int n = L == 0 ? n0 : (L == 1 ? n1 : n2);
    if ((int)blockIdx.x * 1024 >= n) return;
    const uint32_t* v = deg3 + (L == 0 ? 0 : (L == 1 ? no1 : no2));
    uint32_t* bsum = bsum3 + L * 256;
    __shared__ uint32_t sd[256];
    int tid = threadIdx.x;
    int base = blockIdx.x * 1024 + tid * 4;
    uint32_t s = 0;
    #pragma unroll
    for (int i = 0; i < 4; ++i) { int idx = base + i; if (idx < n) s += v[idx]; }
    sd[tid] = s; __syncthreads();
    #pragma unroll
    for (int off = 128; off > 0; off >>= 1) {
        if (tid < off) sd[tid] += sd[tid + off];
        __syncthreads();
    }
    if (tid == 0) bsum[blockIdx.x] = sd[0];
}

// pass2: serial exclusive scan of block sums per layer; blockIdx.x = layer
__global__ void scan2b_kernel(uint32_t* __restrict__ bsum3,
                              uint32_t* __restrict__ rowptr3,
                              int n0, int n1, int n2, int r1, int r2)
{
    if (threadIdx.x != 0) return;
    int L = blockIdx.x;
    int n = L == 0 ? n0 : (L == 1 ? n1 : n2);
    int rp = L == 0 ? 0 : (L == 1 ? r1 : r2);
    uint32_t* bsum = bsum3 + L * 256;
    int nb = (n + 1023) / 1024;
    uint32_t a = 0;
    for (int i = 0; i < nb; ++i) { uint32_t t = bsum[i]; bsum[i] = a; a += t; }
    rowptr3[rp + n] = a;
}

// pass3: local exclusive scan + block offset -> rowptr, cur; blockIdx.y = layer
__global__ __launch_bounds__(256) void scan3b_kernel(
    const uint32_t* __restrict__ deg3, const uint32_t* __restrict__ bsum3,
    uint32_t* __restrict__ rowptr3, uint32_t* __restrict__ cur3,
    int n0, int n1, int n2, int no1, int no2, int r1, int r2)
{
    int L = blockIdx.y;
    int n = L == 0 ? n0 : (L == 1 ? n1 : n2);
    if ((int)blockIdx.x * 1024 >= n) return;
    int noff = L == 0 ? 0 : (L == 1 ? no1 : no2);
    int rp = L == 0 ? 0 : (L == 1 ? r1 : r2);
    const uint32_t* v = deg3 + noff;
    const uint32_t* bsum = bsum3 + L * 256;
    uint32_t* rowptr = rowptr3 + rp;
    uint32_t* cur = cur3 + noff;
    __shared__ uint32_t sd[256];
    int tid = threadIdx.x;
    int base = blockIdx.x * 1024 + tid * 4;
    uint32_t x[4]; uint32_t s = 0;
    #pragma unroll
    for (int i = 0; i < 4; ++i) {
        int idx = base + i;
        x[i] = (idx < n) ? v[idx] : 0u;
        s += x[i];
    }
    sd[tid] = s; __syncthreads();
    uint32_t inc = s;
    #pragma unroll
    for (int off = 1; off < 256; off <<= 1) {
        uint32_t y = (tid >= off) ? sd[tid - off] : 0u;
        __syncthreads();
        inc += y; sd[tid] = inc;
        __syncthreads();
    }
    uint32_t run = bsum[blockIdx.x] + inc - s;
    #pragma unroll
    for (int i = 0; i < 4; ++i) {
        int idx = base + i;
        if (idx < n) { rowptr[idx] = run; cur[idx] = run; run += x[i]; }
    }
}

__global__ __launch_bounds__(256) void csr_fill3_kernel(
    const int* __restrict__ s0, const int* __restrict__ d0,
    const int* __restrict__ s1, const int* __restrict__ d1,
    const int* __restrict__ s2, const int* __restrict__ d2,
    int E0, int E1, int E2, uint32_t* __restrict__ cur3,
    int* __restrict__ elist3, int no1, int no2)
{
    int e = blockIdx.x * 256 + threadIdx.x;
    if (e < E0) {
        uint32_t p = atomicAdd(&cur3[d0[e]], 1u);
        elist3[p] = s0[e];
    } else if (e < E0 + E1) {
        int el = e - E0;
        uint32_t p = atomicAdd(&cur3[no1 + d1[el]], 1u);
        elist3[E0 + p] = s1[el];
    } else if (e < E0 + E1 + E2) {
        int el = e - E0 - E1;
        uint32_t p = atomicAdd(&cur3[no2 + d2[el]], 1u);
        elist3[E0 + E1 + p] = s2[el];
    }
}

// ---------------------------------------------------------------------------
// Batched type bucketing over all 3 layers (types-only dependent)
// ---------------------------------------------------------------------------
__global__ __launch_bounds__(256) void count3_kernel(
    const int* __restrict__ t0, const int* __restrict__ t1, const int* __restrict__ t2,
    int n0, int n1, int n2, uint32_t* __restrict__ tcnt)
{
    __shared__ uint32_t lh[24];
    int tid = threadIdx.x;
    if (tid < 24) lh[tid] = 0;
    __syncthreads();
    int i = blockIdx.x * 256 + tid;
    if (i < n0) atomicAdd(&lh[t0[i]], 1u);
    else if (i < n0 + n1) atomicAdd(&lh[8 + t1[i - n0]], 1u);
    else if (i < n0 + n1 + n2) atomicAdd(&lh[16 + t2[i - n0 - n1]], 1u);
    __syncthreads();
    if (tid < 24 && lh[tid]) atomicAdd(&tcnt[tid], lh[tid]);
}

__global__ void scan_types3_kernel(const uint32_t* __restrict__ tcnt,
                                   int* __restrict__ boff, uint32_t* __restrict__ tcur)
{
    if (threadIdx.x != 0) return;
    for (int L = 0; L < 3; ++L) {
        int a = 0;
        for (int t = 0; t < 8; ++t) {
            boff[L * 9 + t] = a; tcur[L * 8 + t] = (uint32_t)a;
            a += (int)tcnt[L * 8 + t];
        }
        boff[L * 9 + 8] = a;
    }
}

__global__ __launch_bounds__(256) void order3_kernel(
    const int* __restrict__ t0, const int* __restrict__ t1, const int* __restrict__ t2,
    int n0, int n1, int n2, uint32_t* __restrict__ tcur,
    int* __restrict__ order3, int no1, int no2)
{
    __shared__ uint32_t lh[24], lbase[24];
    int tid = threadIdx.x;
    if (tid < 24) lh[tid] = 0;
    __syncthreads();
    int i = blockIdx.x * 256 + tid;
    int slot = -1, idx = 0; uint32_t r = 0;
    if (i < n0) { idx = i; slot = t0[idx]; }
    else if (i < n0 + n1) { idx = i - n0; slot = 8 + t1[idx]; }
    else if (i < n0 + n1 + n2) { idx = i - n0 - n1; slot = 16 + t2[idx]; }
    if (slot >= 0) r = atomicAdd(&lh[slot], 1u);
    __syncthreads();
    if (tid < 24 && lh[tid]) lbase[tid] = atomicAdd(&tcur[tid], lh[tid]);
    __syncthreads();
    if (slot >= 0) {
        int noff = slot < 8 ? 0 : (slot < 16 ? no1 : no2);
        order3[noff + lbase[slot] + r] = idx;
    }
}

// ---------------------------------------------------------------------------
// Gather-aggregate (bf16-packed input rows, 256B/row): one wave per dst node.
// f32 accumulate; writes normalized agg as bf16 hi/lo packed.
// ---------------------------------------------------------------------------
__global__ __launch_bounds__(256) void aggregate_kernel(
    const uint32_t* __restrict__ hbf, const uint32_t* __restrict__ rowptr,
    const int* __restrict__ elist, uint32_t* __restrict__ agghi,
    uint32_t* __restrict__ agglo, int nout)
{
    int n = blockIdx.x * 4 + (threadIdx.x >> 6);
    if (n >= nout) return;
    int lane = threadIdx.x & 63;
    uint32_t beg = rowptr[n], end = rowptr[n + 1];
    const uint32_t* base = hbf + lane;
    float ax = 0.f, ay = 0.f;
    uint32_t e = beg;
    for (; e + 4 <= end; e += 4) {
        int s0 = elist[e], s1 = elist[e + 1], s2 = elist[e + 2], s3 = elist[e + 3];
        uint32_t u0 = base[(size_t)s0 * 64];
        uint32_t u1 = base[(size_t)s1 * 64];
        uint32_t u2 = base[(size_t)s2 * 64];
        uint32_t u3 = base[(size_t)s3 * 64];
        ax += (bflo(u0) + bflo(u1)) + (bflo(u2) + bflo(u3));
        ay += (bfhi(u0) + bfhi(u1)) + (bfhi(u2) + bfhi(u3));
    }
    for (; e < end; ++e) {
        uint32_t u0 = base[(size_t)elist[e] * 64];
        ax += bflo(u0); ay += bfhi(u0);
    }
    float sc = 1.0f / fmaxf((float)(end - beg), 1.0f);
    ax *= sc; ay *= sc;
    ushort hx = bf16_rn(ax); ushort lx = bf16_rn(ax - bf16_f(hx));
    ushort hy = bf16_rn(ay); ushort ly = bf16_rn(ay - bf16_f(hy));
    agghi[(size_t)n * 64 + lane] = (uint32_t)hx | ((uint32_t)hy << 16);
    agglo[(size_t)n * 64 + lane] = (uint32_t)lx | ((uint32_t)ly << 16);
}

// ---------------------------------------------------------------------------
// Weight prep: src f32 [8][128][C] (k-major) -> dst bf16 hi/lo [8][C][128]
// transposed + XOR-swizzled: chunk' = (k>>3) ^ (c&15).
// ---------------------------------------------------------------------------
__global__ __launch_bounds__(256) void prep_wt_kernel(
    const float* __restrict__ src8, ushort* __restrict__ dsthi,
    ushort* __restrict__ dstlo, int C)
{
    int t = blockIdx.x;
    const float* S = src8 + (size_t)t * 128 * C;
    ushort* DH = dsthi + (size_t)t * C * 128;
    ushort* DL = dstlo + (size_t)t * C * 128;
    for (int idx = threadIdx.x; idx < 128 * C; idx += 256) {
        int k = idx / C, c = idx % C;
        float v = S[(size_t)k * C + c];
        ushort hi = bf16_rn(v);
        ushort lo = bf16_rn(v - bf16_f(hi));
        int pos = c * 128 + ((((k >> 3) ^ (c & 15)) << 3) | (k & 7));
        DH[pos] = hi; DL[pos] = lo;
    }
}

// ---------------------------------------------------------------------------
// MFMA GEMM (split-bf16): out[n] = [relu](agg[n] @ W[t] + b[t]) [* dropout]
// 512 thr = 8 waves; tile M=128 x N=DOUT, K=128.
// OUTBF: pack adjacent output cols via __shfl_xor(1) and store bf16x2.
// ---------------------------------------------------------------------------
template<int DOUT, bool RELU, bool DROP, bool OUTBF>
__global__ __launch_bounds__(512) void mfma_gemm_kernel(
    const uint32_t* __restrict__ agghi, const uint32_t* __restrict__ agglo,
    const int* __restrict__ order, const int* __restrict__ off,
    const ushort* __restrict__ WThi, const ushort* __restrict__ WTlo,
    const float* __restrict__ bias8, void* __restrict__ houtv,
    uint32_t fk0, uint32_t fk1)
{
    __shared__ ushort AH[128 * 128];
    __shared__ ushort AL[128 * 128];
    __shared__ ushort WH[DOUT * 128];
    __shared__ ushort WL[DOUT * 128];
    __shared__ int ND[128];

    int t = blockIdx.y;
    int b0 = off[t] + blockIdx.x * 128;
    int bend = off[t + 1];
    if (b0 >= bend) return;
    int m = bend - b0; if (m > 128) m = 128;
    int tid = threadIdx.x;

    if (tid < 128) ND[tid] = (tid < m) ? order[b0 + tid] : -1;
    __syncthreads();

    // stage W (pre-transposed, pre-swizzled -> straight copy)
    {
        const float4* sh = (const float4*)(WThi + (size_t)t * DOUT * 128);
        const float4* sl = (const float4*)(WTlo + (size_t)t * DOUT * 128);
        float4* dh = (float4*)WH; float4* dl = (float4*)WL;
        #pragma unroll
        for (int it = 0; it < DOUT * 16 / 512; ++it) {
            int c = it * 512 + tid;
            dh[c] = sh[c]; dl[c] = sl[c];
        }
    }
    // stage A: gather rows via ND, swizzle chunk by tile-local (row&15)
    {
        const float4* gh = (const float4*)agghi;
        const float4* gl = (const float4*)agglo;
        float4* dh = (float4*)AH; float4* dl = (float4*)AL;
        #pragma unroll
        for (int it = 0; it < 4; ++it) {
            int g = it * 512 + tid;
            int row = g >> 4, ch = g & 15;
            int nd = ND[row];
            float4 vh = make_float4(0.f, 0.f, 0.f, 0.f);
            float4 vl = make_float4(0.f, 0.f, 0.f, 0.f);
            if (nd >= 0) {
                vh = gh[(size_t)nd * 16 + ch];
                vl = gl[(size_t)nd * 16 + ch];
            }
            int dch = ch ^ (row & 15);
            dh[row * 16 + dch] = vh;
            dl[row * 16 + dch] = vl;
        }
    }
    __syncthreads();

    int wid = tid >> 6, lane = tid & 63;
    int r15 = lane & 15, q = lane >> 4;
    constexpr int NF = DOUT / 16;
    f32x4 acc[NF];
    #pragma unroll
    for (int i = 0; i < NF; ++i) acc[i] = (f32x4){0.f, 0.f, 0.f, 0.f};

    int arow = wid * 16 + r15;
    const bf16x8* AHp = (const bf16x8*)AH;
    const bf16x8* ALp = (const bf16x8*)AL;
    const bf16x8* WHp = (const bf16x8*)WH;
    const bf16x8* WLp = (const bf16x8*)WL;

    #pragma unroll
    for (int ks = 0; ks < 4; ++ks) {
        int sch = (q + ks * 4) ^ r15;
        bf16x8 ah = AHp[arow * 16 + sch];
        bf16x8 al = ALp[arow * 16 + sch];
        #pragma unroll
        for (int nf = 0; nf < NF; ++nf) {
            int col = nf * 16 + r15;
            bf16x8 bh = WHp[col * 16 + sch];
            bf16x8 bl = WLp[col * 16 + sch];
            acc[nf] = __builtin_amdgcn_mfma_f32_16x16x32_bf16(ah, bh, acc[nf], 0, 0, 0);
            acc[nf] = __builtin_amdgcn_mfma_f32_16x16x32_bf16(ah, bl, acc[nf], 0, 0, 0);
            acc[nf] = __builtin_amdgcn_mfma_f32_16x16x32_bf16(al, bh, acc[nf], 0, 0, 0);
        }
    }

    // epilogue: C/D row = wid*16 + q*4 + r, col = nf*16 + r15
    int ndr[4];
    #pragma unroll
    for (int r = 0; r < 4; ++r) ndr[r] = ND[wid * 16 + q * 4 + r];
    const float* bptr = bias8 + (size_t)t * DOUT;

    #pragma unroll
    for (int nf = 0; nf < NF; ++nf) {
        int col = nf * 16 + r15;
        float bv = bptr[col];
        float vr[4];
        #pragma unroll
        for (int r = 0; r < 4; ++r) {
            float v = acc[nf][r] + bv;
            if (RELU) v = fmaxf(v, 0.f);
            if (DROP) {
                int nd = ndr[r] < 0 ? 0 : ndr[r];
                v *= drop_scale(fk0, fk1, (uint32_t)nd * 128u + (uint32_t)col);
            }
            vr[r] = v;
        }
        if (OUTBF) {
            uint32_t* hb = (uint32_t*)houtv;
            #pragma unroll
            for (int r = 0; r < 4; ++r) {
                float w = __shfl_xor(vr[r], 1, 64);
                if ((lane & 1) == 0 && ndr[r] >= 0)
                    hb[(size_t)ndr[r] * (DOUT / 2) + (col >> 1)] = pack2bf(vr[r], w);
            }
        } else {
            float* ho = (float*)houtv;
            #pragma unroll
            for (int r = 0; r < 4; ++r)
                if (ndr[r] >= 0) ho[(size_t)ndr[r] * DOUT + col] = vr[r];
        }
    }
}

// ---------------------------------------------------------------------------
// fc fusion: Wf[t] = W[t] @ fcW (128x64 f32), bf[t] = b[t] @ fcW + fcb
// ---------------------------------------------------------------------------
__global__ __launch_bounds__(256) void fuse_fc_kernel(
    const float* __restrict__ convW, const float* __restrict__ convb,
    const float* __restrict__ fcW, const float* __restrict__ fcb,
    float* __restrict__ Wf, float* __restrict__ bf)
{
    __shared__ float F[128 * 64];
    int t = blockIdx.x, tid = threadIdx.x;
    #pragma unroll
    for (int it = 0; it < 8; ++it) {
        int idx4 = (it * 256 + tid) * 4;
        *(float4*)&F[idx4] = *(const float4*)&fcW[idx4];
    }
    __syncthreads();

    int r = tid >> 1, cb = (tid & 1) * 32;
    const float* Wrow = convW + (size_t)t * 16384 + (size_t)r * 128;
    float acc[32];
    #pragma unroll
    for (int c = 0; c < 32; ++c) acc[c] = 0.f;
    for (int k = 0; k < 128; ++k) {
        float w = Wrow[k];
        #pragma unroll
        for (int c = 0; c < 32; ++c) acc[c] += w * F[k * 64 + cb + c];
    }
    float* outp = Wf + (size_t)t * 8192 + (size_t)r * 64 + cb;
    #pragma unroll
    for (int c = 0; c < 32; ++c) outp[c] = acc[c];

    if (tid < 64) {
        float a = fcb[tid];
        const float* bt = convb + (size_t)t * 128;
        for (int k = 0; k < 128; ++k) a += bt[k] * F[k * 64 + tid];
        bf[(size_t)t * 64 + tid] = a;
    }
}

// ---------------------------------------------------------------------------
extern "C" void kernel_launch(void* const* d_in, const int* in_sizes, int n_in,
                              void* d_out, int out_size, void* d_ws, size_t ws_size,
                              hipStream_t stream)
{
    const float* features = (const float*)d_in[0];
    const int*   src0 = (const int*)d_in[1];
    const int*   dst0 = (const int*)d_in[2];
    const int*   types1 = (const int*)d_in[3];
    const int*   src1 = (const int*)d_in[4];
    const int*   dst1 = (const int*)d_in[5];
    const int*   types2 = (const int*)d_in[6];
    const int*   src2 = (const int*)d_in[7];
    const int*   dst2 = (const int*)d_in[8];
    const int*   types3 = (const int*)d_in[9];
    const float* convW = (const float*)d_in[10];
    const float* convb = (const float*)d_in[11];
    const float* fcW   = (const float*)d_in[12];
    const float* fcb   = (const float*)d_in[13];

    int N0 = in_sizes[0] / 128;
    int E0 = in_sizes[1], N1 = in_sizes[3];
    int E1 = in_sizes[4], N2 = in_sizes[6];
    int E2 = in_sizes[7], N3 = in_sizes[9];
    int totalN = N1 + N2 + N3;
    int totalE = E0 + E1 + E2;
    int no1 = N1, no2 = N1 + N2;                 // node offsets
    int r1 = N1 + 1, r2 = N1 + 1 + N2 + 1;       // rowptr offsets
    int maxN = N1 > N2 ? N1 : N2; if (N3 > maxN) maxN = N3;

    char* ws = (char*)d_ws;
    size_t woff = 0;
    auto alloc = [&](size_t bytes) -> void* {
        void* p = ws + woff;
        woff = (woff + bytes + 255) & ~(size_t)255;
        return p;
    };
    uint32_t* fbf     = (uint32_t*)alloc((size_t)N0 * 64 * 4);    // packed bf16 features
    uint32_t* hbf     = fbf;                                      // alias: h after L0 agg done
    uint32_t* aggHi   = (uint32_t*)alloc((size_t)maxN * 64 * 4);
    uint32_t* aggLo   = (uint32_t*)alloc((size_t)maxN * 64 * 4);
    uint32_t* deg3    = (uint32_t*)alloc((size_t)totalN * 4);
    uint32_t* tcnt    = (uint32_t*)alloc(24 * 4);
    uint32_t* rowptr3 = (uint32_t*)alloc((size_t)(totalN + 3) * 4);
    uint32_t* cur3    = (uint32_t*)alloc((size_t)totalN * 4);
    int*      elist3  = (int*)alloc((size_t)totalE * 4);
    int*      order3  = (int*)alloc((size_t)totalN * 4);
    uint32_t* bsum3   = (uint32_t*)alloc(768 * 4);
    int*      boff    = (int*)alloc(27 * 4);
    uint32_t* tcur    = (uint32_t*)alloc(24 * 4);
    float*    Wf      = (float*)alloc((size_t)8 * 128 * 64 * 4);
    float*    bfb     = (float*)alloc((size_t)8 * 64 * 4);
    ushort*   WThi    = (ushort*)alloc((size_t)8 * 128 * 128 * 2);
    ushort*   WTlo    = (ushort*)alloc((size_t)8 * 128 * 128 * 2);
    ushort*   WfThi   = (ushort*)alloc((size_t)8 * 64 * 128 * 2);
    ushort*   WfTlo   = (ushort*)alloc((size_t)8 * 64 * 128 * 2);
    (void)ws_size; (void)n_in; (void)out_size;

    // --- one-time prep ---
    fcvt_kernel<<<4096, 256, 0, stream>>>(
        (const float4*)features, (uint2*)fbf, (long long)N0 * 32);
    prep_wt_kernel<<<8, 256, 0, stream>>>(convW, WThi, WTlo, 128);
    fuse_fc_kernel<<<8, 256, 0, stream>>>(convW, convb, fcW, fcb, Wf, bfb);
    prep_wt_kernel<<<8, 256, 0, stream>>>(Wf, WfThi, WfTlo, 64);

    // --- batched CSR build (h-independent) ---
    hipMemsetAsync(deg3, 0, (size_t)totalN * 4, stream);
    hipMemsetAsync(tcnt, 0, 24 * 4, stream);
    int eblk = (totalE + 255) / 256;
    hist3_kernel<<<eblk, 256, 0, stream>>>(dst0, dst1, dst2, E0, E1, E2, deg3, no1, no2);
    int nbmax = (N1 + 1023) / 1024;
    {
        int nb2 = (N2 + 1023) / 1024, nb3 = (N3 + 1023) / 1024;
        if (nb2 > nbmax) nbmax = nb2;
        if (nb3 > nbmax) nbmax = nb3;
    }
    scan1b_kernel<<<dim3(nbmax, 3), 256, 0, stream>>>(deg3, bsum3, N1, N2, N3, no1, no2);
    scan2b_kernel<<<3, 64, 0, stream>>>(bsum3, rowptr3, N1, N2, N3, r1, r2);
    scan3b_kernel<<<dim3(nbmax, 3), 256, 0, stream>>>(
        deg3, bsum3, rowptr3, cur3, N1, N2, N3, no1, no2, r1, r2);
    csr_fill3_kernel<<<eblk, 256, 0, stream>>>(
        src0, dst0, src1, dst1, src2, dst2, E0, E1, E2, cur3, elist3, no1, no2);

    // --- batched type bucketing (h-independent) ---
    int nblk = (totalN + 255) / 256;
    count3_kernel<<<nblk, 256, 0, stream>>>(types1, types2, types3, N1, N2, N3, tcnt);
    scan_types3_kernel<<<1, 64, 0, stream>>>(tcnt, boff, tcur);
    order3_kernel<<<nblk, 256, 0, stream>>>(
        types1, types2, types3, N1, N2, N3, tcur, order3, no1, no2);

    // fold-in keys
    uint32_t fk1a, fk1b, fk2a, fk2b;
    tf2x32(0u, 42u, 0u, 1u, &fk1a, &fk1b);
    tf2x32(0u, 42u, 0u, 2u, &fk2a, &fk2b);

    // --- layer 0 ---
    aggregate_kernel<<<(N1 + 3) / 4, 256, 0, stream>>>(
        fbf, rowptr3, elist3, aggHi, aggLo, N1);
    mfma_gemm_kernel<128, true, true, true><<<dim3((N1 + 127) / 128, 8), 512, 0, stream>>>(
        aggHi, aggLo, order3, boff, WThi, WTlo, convb, hbf, fk1a, fk1b);

    // --- layer 1 ---
    aggregate_kernel<<<(N2 + 3) / 4, 256, 0, stream>>>(
        hbf, rowptr3 + r1, elist3 + E0, aggHi, aggLo, N2);
    mfma_gemm_kernel<128, true, true, true><<<dim3((N2 + 127) / 128, 8), 512, 0, stream>>>(
        aggHi, aggLo, order3 + no1, boff + 9, WThi, WTlo, convb, hbf, fk2a, fk2b);

    // --- layer 2 (fc folded, f32 out) ---
    aggregate_kernel<<<(N3 + 3) / 4, 256, 0, stream>>>(
        hbf, rowptr3 + r2, elist3 + E0 + E1, aggHi, aggLo, N3);
    mfma_gemm_kernel<64, false, false, false><<<dim3((N3 + 127) / 128, 8), 512, 0, stream>>>(
        aggHi, aggLo, order3 + no2, boff + 18, WfThi, WfTlo, bfb, d_out, 0u, 0u);
}

// Round 6
// 790.469 us; speedup vs baseline: 10.1444x; 1.1273x over previous
//
#include <hip/hip_runtime.h>
#include <cstdint>
#include <cstddef>

// ---------------------------------------------------------------------------
// JAX threefry2x32 (20 rounds). fold_in(key(42), i) = threefry((0,42),(0,i))
// partitionable 32-bit random_bits: bits = o0 ^ o1 (XOR-fold)   [validated r2]
// uniform: u = bitcast((bits>>9)|0x3f800000) - 1.0f ; keep iff u < 0.9f
// ---------------------------------------------------------------------------
__host__ __device__ inline void tf2x32(uint32_t k0, uint32_t k1,
                                       uint32_t x0, uint32_t x1,
                                       uint32_t* o0, uint32_t* o1)
{
    uint32_t ks2 = k0 ^ k1 ^ 0x1BD11BDAu;
    x0 += k0; x1 += k1;
#define TF_R(r) do { x0 += x1; x1 = (x1 << (r)) | (x1 >> (32 - (r))); x1 ^= x0; } while (0)
    TF_R(13); TF_R(15); TF_R(26); TF_R(6);
    x0 += k1;  x1 += ks2 + 1u;
    TF_R(17); TF_R(29); TF_R(16); TF_R(24);
    x0 += ks2; x1 += k0 + 2u;
    TF_R(13); TF_R(15); TF_R(26); TF_R(6);
    x0 += k0;  x1 += k1 + 3u;
    TF_R(17); TF_R(29); TF_R(16); TF_R(24);
    x0 += k1;  x1 += ks2 + 4u;
    TF_R(13); TF_R(15); TF_R(26); TF_R(6);
    x0 += ks2; x1 += k0 + 5u;
#undef TF_R
    *o0 = x0; *o1 = x1;
}

__device__ inline float drop_scale(uint32_t fk0, uint32_t fk1, uint32_t idx)
{
    uint32_t o0, o1;
    tf2x32(fk0, fk1, 0u, idx, &o0, &o1);
    uint32_t bits = o0 ^ o1;
    float u = __uint_as_float((bits >> 9) | 0x3f800000u) - 1.0f;
    return (u < 0.9f) ? (1.0f / 0.9f) : 0.0f;
}

// bf16 helpers (round-to-nearest-even)
__device__ inline ushort bf16_rn(float f)
{
    uint32_t u = __float_as_uint(f);
    u += 0x7fffu + ((u >> 16) & 1u);
    return (ushort)(u >> 16);
}
__device__ inline float bf16_f(ushort h) { return __uint_as_float(((uint32_t)h) << 16); }
__device__ inline uint32_t pack2bf(float a, float b)
{
    return (uint32_t)bf16_rn(a) | ((uint32_t)bf16_rn(b) << 16);
}
__device__ inline float bflo(uint32_t u) { return __uint_as_float(u << 16); }
__device__ inline float bfhi(uint32_t u) { return __uint_as_float(u & 0xffff0000u); }

typedef __attribute__((ext_vector_type(8))) short bf16x8;
typedef __attribute__((ext_vector_type(4))) float f32x4;

// ---------------------------------------------------------------------------
// features f32 -> packed bf16x2 (one-time per call, streaming)
// ---------------------------------------------------------------------------
__global__ __launch_bounds__(256) void fcvt_kernel(
    const float4* __restrict__ in, uint2* __restrict__ out, long long n4)
{
    long long stride = (long long)gridDim.x * 256;
    for (long long i = blockIdx.x * 256LL + threadIdx.x; i < n4; i += stride) {
        float4 v = in[i];
        out[i] = make_uint2(pack2bf(v.x, v.y), pack2bf(v.z, v.w));
    }
}

// ---------------------------------------------------------------------------
// Bucketed CSR build. Bucket = dst>>10 (1024 nodes). No global atomics.
// pairs entry: (dstLocal << 22) | src   (src < 2^22, dstLocal < 1024)
// ---------------------------------------------------------------------------
#define EPB 4096   // edges per block in count/scatter passes

// pass A: per-block bucket counts -> cnt[blk][NB]
__global__ __launch_bounds__(256) void bcount_kernel(
    const int* __restrict__ dst, int E, int NB, uint32_t* __restrict__ cnt)
{
    __shared__ uint32_t lh[256];
    int tid = threadIdx.x;
    lh[tid] = 0;
    __syncthreads();
    int base = blockIdx.x * EPB;
    for (int i = tid; i < EPB; i += 256) {
        int e = base + i;
        if (e < E) atomicAdd(&lh[((uint32_t)dst[e]) >> 10], 1u);
    }
    __syncthreads();
    uint32_t* row = cnt + (size_t)blockIdx.x * NB;
    if (tid < NB) row[tid] = lh[tid];
}

// pass S1+S2: bucket totals (column sums) + per-layer exclusive scan -> bo[]
// bo layout: [nb0 buckets][sentinel=E0][nb1][sentinel=E1][nb2][sentinel=E2]
__global__ __launch_bounds__(512) void bscan_kernel(
    const uint32_t* __restrict__ cnt, uint32_t* __restrict__ bo,
    uint32_t* __restrict__ rowptr3,
    int nb0, int nb1, int nb2, int nblk0, int nblk1, int nblk2,
    int cO0, int cO1, int cO2, int N1, int N2, int N3, int r1, int r2)
{
    __shared__ uint32_t tot[344];
    __shared__ uint32_t bol[348];
    int t = threadIdx.x;
    int TB = nb0 + nb1 + nb2;
    if (t < TB) {
        int lb, nblk, cO, NB;
        if (t < nb0) { lb = t; nblk = nblk0; cO = cO0; NB = nb0; }
        else if (t < nb0 + nb1) { lb = t - nb0; nblk = nblk1; cO = cO1; NB = nb1; }
        else { lb = t - nb0 - nb1; nblk = nblk2; cO = cO2; NB = nb2; }
        uint32_t s = 0;
        for (int b = 0; b < nblk; ++b) s += cnt[cO + (size_t)b * NB + lb];
        tot[t] = s;
    }
    __syncthreads();
    if (t < 3) {
        int nb = t == 0 ? nb0 : (t == 1 ? nb1 : nb2);
        int g0 = t == 0 ? 0 : (t == 1 ? nb0 : nb0 + nb1);
        int gi0 = g0 + t;
        uint32_t run = 0;
        for (int i = 0; i < nb; ++i) { bol[gi0 + i] = run; run += tot[g0 + i]; }
        bol[gi0 + nb] = run;
        int rp = t == 0 ? 0 : (t == 1 ? r1 : r2);
        int N = t == 0 ? N1 : (t == 1 ? N2 : N3);
        rowptr3[rp + N] = run;
    }
    __syncthreads();
    for (int i = t; i < TB + 3; i += 512) bo[i] = bol[i];
}

// pass S3: rewrite cnt columns into running per-(block,bucket) bases
__global__ __launch_bounds__(256) void brebase_kernel(
    const uint32_t* __restrict__ bo, uint32_t* __restrict__ cnt,
    int nb0, int nb1, int nb2, int nblk0, int nblk1, int nblk2,
    int cO0, int cO1, int cO2)
{
    int t = blockIdx.x * 256 + threadIdx.x;
    int TB = nb0 + nb1 + nb2;
    if (t >= TB) return;
    int layer, lb, nblk, cO, NB;
    if (t < nb0) { layer = 0; lb = t; nblk = nblk0; cO = cO0; NB = nb0; }
    else if (t < nb0 + nb1) { layer = 1; lb = t - nb0; nblk = nblk1; cO = cO1; NB = nb1; }
    else { layer = 2; lb = t - nb0 - nb1; nblk = nblk2; cO = cO2; NB = nb2; }
    uint32_t base = bo[t + layer];
    for (int b = 0; b < nblk; ++b) {
        size_t ix = cO + (size_t)b * NB + lb;
        uint32_t old = cnt[ix]; cnt[ix] = base; base += old;
    }
}

// pass B: scatter edges into bucket-grouped pairs (runs per bucket -> low amp)
__global__ __launch_bounds__(256) void bscatter_kernel(
    const int* __restrict__ src, const int* __restrict__ dst, int E, int NB,
    const uint32_t* __restrict__ cntL, uint32_t* __restrict__ pairs)
{
    __shared__ uint32_t rank[256];
    int tid = threadIdx.x;
    rank[tid] = 0;
    __syncthreads();
    const uint32_t* basep = cntL + (size_t)blockIdx.x * NB;
    int base = blockIdx.x * EPB;
    for (int i = tid; i < EPB; i += 256) {
        int e = base + i;
        if (e < E) {
            uint32_t d = (uint32_t)dst[e];
            uint32_t bk = d >> 10;
            uint32_t r = atomicAdd(&rank[bk], 1u);
            uint32_t pos = basep[bk] + r;
            pairs[pos] = ((d & 1023u) << 22) | (uint32_t)src[e];
        }
    }
}

// pass C: one block per bucket: LDS hist -> scan -> rowptr + fine elist fill
__global__ __launch_bounds__(256) void bfill_kernel(
    const uint32_t* __restrict__ bo, const uint32_t* __restrict__ pairs,
    int* __restrict__ elist3, uint32_t* __restrict__ rowptr3,
    int nb0, int nb1, int nb2, int N1, int N2, int N3,
    int E0, int E1, int r1, int r2)
{
    __shared__ uint32_t hist[1024];
    __shared__ uint32_t cur[1024];
    __shared__ uint32_t psum[256];
    int g = blockIdx.x, tid = threadIdx.x;
    int layer, lb, N, Eoff, rp;
    if (g < nb0) { layer = 0; lb = g; N = N1; Eoff = 0; rp = 0; }
    else if (g < nb0 + nb1) { layer = 1; lb = g - nb0; N = N2; Eoff = E0; rp = r1; }
    else { layer = 2; lb = g - nb0 - nb1; N = N3; Eoff = E0 + E1; rp = r2; }
    uint32_t off = bo[g + layer], end = bo[g + layer + 1];
    int nodeBase = lb << 10;
    int nodesIn = N - nodeBase; if (nodesIn > 1024) nodesIn = 1024;

    #pragma unroll
    for (int i = 0; i < 4; ++i) hist[tid * 4 + i] = 0;
    __syncthreads();
    for (uint32_t e = off + tid; e < end; e += 256)
        atomicAdd(&hist[pairs[Eoff + e] >> 22], 1u);
    __syncthreads();

    // exclusive scan of hist -> cur (+off)
    uint32_t x[4]; uint32_t s = 0;
    #pragma unroll
    for (int i = 0; i < 4; ++i) { x[i] = hist[tid * 4 + i]; s += x[i]; }
    psum[tid] = s; __syncthreads();
    uint32_t inc = s;
    #pragma unroll
    for (int o = 1; o < 256; o <<= 1) {
        uint32_t y = (tid >= o) ? psum[tid - o] : 0u;
        __syncthreads();
        inc += y; psum[tid] = inc;
        __syncthreads();
    }
    uint32_t run = off + inc - s;
    #pragma unroll
    for (int i = 0; i < 4; ++i) { cur[tid * 4 + i] = run; run += x[i]; }
    __syncthreads();

    for (int i = tid; i < nodesIn; i += 256)
        rowptr3[rp + nodeBase + i] = cur[i];
    __syncthreads();

    for (uint32_t e = off + tid; e < end; e += 256) {
        uint32_t pk = pairs[Eoff + e];
        uint32_t pos = atomicAdd(&cur[pk >> 22], 1u);
        elist3[Eoff + pos] = (int)(pk & 0x3FFFFFu);
    }
}

// ---------------------------------------------------------------------------
// Batched type bucketing over all 3 layers (types-only dependent)
// ---------------------------------------------------------------------------
__global__ __launch_bounds__(256) void count3_kernel(
    const int* __restrict__ t0, const int* __restrict__ t1, const int* __restrict__ t2,
    int n0, int n1, int n2, uint32_t* __restrict__ tcnt)
{
    __shared__ uint32_t lh[24];
    int tid = threadIdx.x;
    if (tid < 24) lh[tid] = 0;
    __syncthreads();
    int i = blockIdx.x * 256 + tid;
    if (i < n0) atomicAdd(&lh[t0[i]], 1u);
    else if (i < n0 + n1) atomicAdd(&lh[8 + t1[i - n0]], 1u);
    else if (i < n0 + n1 + n2) atomicAdd(&lh[16 + t2[i - n0 - n1]], 1u);
    __syncthreads();
    if (tid < 24 && lh[tid]) atomicAdd(&tcnt[tid], lh[tid]);
}

__global__ void scan_types3_kernel(const uint32_t* __restrict__ tcnt,
                                   int* __restrict__ boff, uint32_t* __restrict__ tcur)
{
    if (threadIdx.x != 0) return;
    for (int L = 0; L < 3; ++L) {
        int a = 0;
        for (int t = 0; t < 8; ++t) {
            boff[L * 9 + t] = a; tcur[L * 8 + t] = (uint32_t)a;
            a += (int)tcnt[L * 8 + t];
        }
        boff[L * 9 + 8] = a;
    }
}

__global__ __launch_bounds__(256) void order3_kernel(
    const int* __restrict__ t0, const int* __restrict__ t1, const int* __restrict__ t2,
    int n0, int n1, int n2, uint32_t* __restrict__ tcur,
    int* __restrict__ order3, int no1, int no2)
{
    __shared__ uint32_t lh[24], lbase[24];
    int tid = threadIdx.x;
    if (tid < 24) lh[tid] = 0;
    __syncthreads();
    int i = blockIdx.x * 256 + tid;
    int slot = -1, idx = 0; uint32_t r = 0;
    if (i < n0) { idx = i; slot = t0[idx]; }
    else if (i < n0 + n1) { idx = i - n0; slot = 8 + t1[idx]; }
    else if (i < n0 + n1 + n2) { idx = i - n0 - n1; slot = 16 + t2[idx]; }
    if (slot >= 0) r = atomicAdd(&lh[slot], 1u);
    __syncthreads();
    if (tid < 24 && lh[tid]) lbase[tid] = atomicAdd(&tcur[tid], lh[tid]);
    __syncthreads();
    if (slot >= 0) {
        int noff = slot < 8 ? 0 : (slot < 16 ? no1 : no2);
        order3[noff + lbase[slot] + r] = idx;
    }
}

// ---------------------------------------------------------------------------
// Gather-aggregate (bf16-packed input rows, 256B/row): one wave per dst node.
// f32 accumulate; writes normalized agg as bf16 hi/lo packed.
// ---------------------------------------------------------------------------
__global__ __launch_bounds__(256) void aggregate_kernel(
    const uint32_t* __restrict__ hbf, const uint32_t* __restrict__ rowptr,
    const int* __restrict__ elist, uint32_t* __restrict__ agghi,
    uint32_t* __restrict__ agglo, int nout)
{
    int n = blockIdx.x * 4 + (threadIdx.x >> 6);
    if (n >= nout) return;
    int lane = threadIdx.x & 63;
    uint32_t beg = rowptr[n], end = rowptr[n + 1];
    const uint32_t* base = hbf + lane;
    float ax = 0.f, ay = 0.f;
    uint32_t e = beg;
    for (; e + 4 <= end; e += 4) {
        int s0 = elist[e], s1 = elist[e + 1], s2 = elist[e + 2], s3 = elist[e + 3];
        uint32_t u0 = base[(size_t)s0 * 64];
        uint32_t u1 = base[(size_t)s1 * 64];
        uint32_t u2 = base[(size_t)s2 * 64];
        uint32_t u3 = base[(size_t)s3 * 64];
        ax += (bflo(u0) + bflo(u1)) + (bflo(u2) + bflo(u3));
        ay += (bfhi(u0) + bfhi(u1)) + (bfhi(u2) + bfhi(u3));
    }
    for (; e < end; ++e) {
        uint32_t u0 = base[(size_t)elist[e] * 64];
        ax += bflo(u0); ay += bfhi(u0);
    }
    float sc = 1.0f / fmaxf((float)(end - beg), 1.0f);
    ax *= sc; ay *= sc;
    ushort hx = bf16_rn(ax); ushort lx = bf16_rn(ax - bf16_f(hx));
    ushort hy = bf16_rn(ay); ushort ly = bf16_rn(ay - bf16_f(hy));
    agghi[(size_t)n * 64 + lane] = (uint32_t)hx | ((uint32_t)hy << 16);
    agglo[(size_t)n * 64 + lane] = (uint32_t)lx | ((uint32_t)ly << 16);
}

// ---------------------------------------------------------------------------
// Weight prep: src f32 [8][128][C] (k-major) -> dst bf16 hi/lo [8][C][128]
// transposed + XOR-swizzled: chunk' = (k>>3) ^ (c&15).
// ---------------------------------------------------------------------------
__global__ __launch_bounds__(256) void prep_wt_kernel(
    const float* __restrict__ src8, ushort* __restrict__ dsthi,
    ushort* __restrict__ dstlo, int C)
{
    int t = blockIdx.x;
    const float* S = src8 + (size_t)t * 128 * C;
    ushort* DH = dsthi + (size_t)t * C * 128;
    ushort* DL = dstlo + (size_t)t * C * 128;
    for (int idx = threadIdx.x; idx < 128 * C; idx += 256) {
        int k = idx / C, c = idx % C;
        float v = S[(size_t)k * C + c];
        ushort hi = bf16_rn(v);
        ushort lo = bf16_rn(v - bf16_f(hi));
        int pos = c * 128 + ((((k >> 3) ^ (c & 15)) << 3) | (k & 7));
        DH[pos] = hi; DL[pos] = lo;
    }
}

// ---------------------------------------------------------------------------
// MFMA GEMM (split-bf16): out[n] = [relu](agg[n] @ W[t] + b[t]) [* dropout]
// 512 thr = 8 waves; tile M=128 x N=DOUT, K=128.
// OUTBF: pack adjacent output cols via __shfl_xor(1) and store bf16x2.
// ---------------------------------------------------------------------------
template<int DOUT, bool RELU, bool DROP, bool OUTBF>
__global__ __launch_bounds__(512) void mfma_gemm_kernel(
    const uint32_t* __restrict__ agghi, const uint32_t* __restrict__ agglo,
    const int* __restrict__ order, const int* __restrict__ off,
    const ushort* __restrict__ WThi, const ushort* __restrict__ WTlo,
    const float* __restrict__ bias8, void* __restrict__ houtv,
    uint32_t fk0, uint32_t fk1)
{
    __shared__ ushort AH[128 * 128];
    __shared__ ushort AL[128 * 128];
    __shared__ ushort WH[DOUT * 128];
    __shared__ ushort WL[DOUT * 128];
    __shared__ int ND[128];

    int t = blockIdx.y;
    int b0 = off[t] + blockIdx.x * 128;
    int bend = off[t + 1];
    if (b0 >= bend) return;
    int m = bend - b0; if (m > 128) m = 128;
    int tid = threadIdx.x;

    if (tid < 128) ND[tid] = (tid < m) ? order[b0 + tid] : -1;
    __syncthreads();

    // stage W (pre-transposed, pre-swizzled -> straight copy)
    {
        const float4* sh = (const float4*)(WThi + (size_t)t * DOUT * 128);
        const float4* sl = (const float4*)(WTlo + (size_t)t * DOUT * 128);
        float4* dh = (float4*)WH; float4* dl = (float4*)WL;
        #pragma unroll
        for (int it = 0; it < DOUT * 16 / 512; ++it) {
            int c = it * 512 + tid;
            dh[c] = sh[c]; dl[c] = sl[c];
        }
    }
    // stage A: gather rows via ND, swizzle chunk by tile-local (row&15)
    {
        const float4* gh = (const float4*)agghi;
        const float4* gl = (const float4*)agglo;
        float4* dh = (float4*)AH; float4* dl = (float4*)AL;
        #pragma unroll
        for (int it = 0; it < 4; ++it) {
            int g = it * 512 + tid;
            int row = g >> 4, ch = g & 15;
            int nd = ND[row];
            float4 vh = make_float4(0.f, 0.f, 0.f, 0.f);
            float4 vl = make_float4(0.f, 0.f, 0.f, 0.f);
            if (nd >= 0) {
                vh = gh[(size_t)nd * 16 + ch];
                vl = gl[(size_t)nd * 16 + ch];
            }
            int dch = ch ^ (row & 15);
            dh[row * 16 + dch] = vh;
            dl[row * 16 + dch] = vl;
        }
    }
    __syncthreads();

    int wid = tid >> 6, lane = tid & 63;
    int r15 = lane & 15, q = lane >> 4;
    constexpr int NF = DOUT / 16;
    f32x4 acc[NF];
    #pragma unroll
    for (int i = 0; i < NF; ++i) acc[i] = (f32x4){0.f, 0.f, 0.f, 0.f};

    int arow = wid * 16 + r15;
    const bf16x8* AHp = (const bf16x8*)AH;
    const bf16x8* ALp = (const bf16x8*)AL;
    const bf16x8* WHp = (const bf16x8*)WH;
    const bf16x8* WLp = (const bf16x8*)WL;

    #pragma unroll
    for (int ks = 0; ks < 4; ++ks) {
        int sch = (q + ks * 4) ^ r15;
        bf16x8 ah = AHp[arow * 16 + sch];
        bf16x8 al = ALp[arow * 16 + sch];
        #pragma unroll
        for (int nf = 0; nf < NF; ++nf) {
            int col = nf * 16 + r15;
            bf16x8 bh = WHp[col * 16 + sch];
            bf16x8 bl = WLp[col * 16 + sch];
            acc[nf] = __builtin_amdgcn_mfma_f32_16x16x32_bf16(ah, bh, acc[nf], 0, 0, 0);
            acc[nf] = __builtin_amdgcn_mfma_f32_16x16x32_bf16(ah, bl, acc[nf], 0, 0, 0);
            acc[nf] = __builtin_amdgcn_mfma_f32_16x16x32_bf16(al, bh, acc[nf], 0, 0, 0);
        }
    }

    // epilogue: C/D row = wid*16 + q*4 + r, col = nf*16 + r15
    int ndr[4];
    #pragma unroll
    for (int r = 0; r < 4; ++r) ndr[r] = ND[wid * 16 + q * 4 + r];
    const float* bptr = bias8 + (size_t)t * DOUT;

    #pragma unroll
    for (int nf = 0; nf < NF; ++nf) {
        int col = nf * 16 + r15;
        float bv = bptr[col];
        float vr[4];
        #pragma unroll
        for (int r = 0; r < 4; ++r) {
            float v = acc[nf][r] + bv;
            if (RELU) v = fmaxf(v, 0.f);
            if (DROP) {
                int nd = ndr[r] < 0 ? 0 : ndr[r];
                v *= drop_scale(fk0, fk1, (uint32_t)nd * 128u + (uint32_t)col);
            }
            vr[r] = v;
        }
        if (OUTBF) {
            uint32_t* hb = (uint32_t*)houtv;
            #pragma unroll
            for (int r = 0; r < 4; ++r) {
                float w = __shfl_xor(vr[r], 1, 64);
                if ((lane & 1) == 0 && ndr[r] >= 0)
                    hb[(size_t)ndr[r] * (DOUT / 2) + (col >> 1)] = pack2bf(vr[r], w);
            }
        } else {
            float* ho = (float*)houtv;
            #pragma unroll
            for (int r = 0; r < 4; ++r)
                if (ndr[r] >= 0) ho[(size_t)ndr[r] * DOUT + col] = vr[r];
        }
    }
}

// ---------------------------------------------------------------------------
// fc fusion: Wf[t] = W[t] @ fcW (128x64 f32), bf[t] = b[t] @ fcW + fcb
// ---------------------------------------------------------------------------
__global__ __launch_bounds__(256) void fuse_fc_kernel(
    const float* __restrict__ convW, const float* __restrict__ convb,
    const float* __restrict__ fcW, const float* __restrict__ fcb,
    float* __restrict__ Wf, float* __restrict__ bf)
{
    __shared__ float F[128 * 64];
    int t = blockIdx.x, tid = threadIdx.x;
    #pragma unroll
    for (int it = 0; it < 8; ++it) {
        int idx4 = (it * 256 + tid) * 4;
        *(float4*)&F[idx4] = *(const float4*)&fcW[idx4];
    }
    __syncthreads();

    int r = tid >> 1, cb = (tid & 1) * 32;
    const float* Wrow = convW + (size_t)t * 16384 + (size_t)r * 128;
    float acc[32];
    #pragma unroll
    for (int c = 0; c < 32; ++c) acc[c] = 0.f;
    for (int k = 0; k < 128; ++k) {
        float w = Wrow[k];
        #pragma unroll
        for (int c = 0; c < 32; ++c) acc[c] += w * F[k * 64 + cb + c];
    }
    float* outp = Wf + (size_t)t * 8192 + (size_t)r * 64 + cb;
    #pragma unroll
    for (int c = 0; c < 32; ++c) outp[c] = acc[c];

    if (tid < 64) {
        float a = fcb[tid];
        const float* bt = convb + (size_t)t * 128;
        for (int k = 0; k < 128; ++k) a += bt[k] * F[k * 64 + tid];
        bf[(size_t)t * 64 + tid] = a;
    }
}

// ---------------------------------------------------------------------------
extern "C" void kernel_launch(void* const* d_in, const int* in_sizes, int n_in,
                              void* d_out, int out_size, void* d_ws, size_t ws_size,
                              hipStream_t stream)
{
    const float* features = (const float*)d_in[0];
    const int*   src0 = (const int*)d_in[1];
    const int*   dst0 = (const int*)d_in[2];
    const int*   types1 = (const int*)d_in[3];
    const int*   src1 = (const int*)d_in[4];
    const int*   dst1 = (const int*)d_in[5];
    const int*   types2 = (const int*)d_in[6];
    const int*   src2 = (const int*)d_in[7];
    const int*   dst2 = (const int*)d_in[8];
    const int*   types3 = (const int*)d_in[9];
    const float* convW = (const float*)d_in[10];
    const float* convb = (const float*)d_in[11];
    const float* fcW   = (const float*)d_in[12];
    const float* fcb   = (const float*)d_in[13];

    int N0 = in_sizes[0] / 128;
    int E0 = in_sizes[1], N1 = in_sizes[3];
    int E1 = in_sizes[4], N2 = in_sizes[6];
    int E2 = in_sizes[7], N3 = in_sizes[9];
    int totalN = N1 + N2 + N3;
    int totalE = E0 + E1 + E2;
    int no1 = N1, no2 = N1 + N2;                 // node offsets
    int r1 = N1 + 1, r2 = N1 + 1 + N2 + 1;       // rowptr offsets
    int maxN = N1 > N2 ? N1 : N2; if (N3 > maxN) maxN = N3;

    // bucket-sort geometry
    int nb0 = (N1 + 1023) >> 10, nb1 = (N2 + 1023) >> 10, nb2 = (N3 + 1023) >> 10;
    int TB = nb0 + nb1 + nb2;
    int nblk0 = (E0 + EPB - 1) / EPB, nblk1 = (E1 + EPB - 1) / EPB, nblk2 = (E2 + EPB - 1) / EPB;
    int cO0 = 0;
    int cO1 = cO0 + nblk0 * nb0;
    int cO2 = cO1 + nblk1 * nb1;
    int cntEntries = cO2 + nblk2 * nb2;

    char* ws = (char*)d_ws;
    size_t woff = 0;
    auto alloc = [&](size_t bytes) -> void* {
        void* p = ws + woff;
        woff = (woff + bytes + 255) & ~(size_t)255;
        return p;
    };
    uint32_t* fbf     = (uint32_t*)alloc((size_t)N0 * 64 * 4);    // packed bf16 features
    uint32_t* hbf     = fbf;                                      // alias: h after L0 agg
    uint32_t* aggHi   = (uint32_t*)alloc((size_t)maxN * 64 * 4);
    uint32_t* pairs   = aggHi;                                    // alias: dead before agg
    uint32_t* aggLo   = (uint32_t*)alloc((size_t)maxN * 64 * 4);
    uint32_t* rowptr3 = (uint32_t*)alloc((size_t)(totalN + 3) * 4);
    int*      elist3  = (int*)alloc((size_t)totalE * 4);
    int*      order3  = (int*)alloc((size_t)totalN * 4);
    uint32_t* cnt     = (uint32_t*)alloc((size_t)cntEntries * 4);
    uint32_t* bo      = (uint32_t*)alloc((size_t)(TB + 3) * 4);
    uint32_t* tcnt    = (uint32_t*)alloc(24 * 4);
    int*      boff    = (int*)alloc(27 * 4);
    uint32_t* tcur    = (uint32_t*)alloc(24 * 4);
    float*    Wf      = (float*)alloc((size_t)8 * 128 * 64 * 4);
    float*    bfb     = (float*)alloc((size_t)8 * 64 * 4);
    ushort*   WThi    = (ushort*)alloc((size_t)8 * 128 * 128 * 2);
    ushort*   WTlo    = (ushort*)alloc((size_t)8 * 128 * 128 * 2);
    ushort*   WfThi   = (ushort*)alloc((size_t)8 * 64 * 128 * 2);
    ushort*   WfTlo   = (ushort*)alloc((size_t)8 * 64 * 128 * 2);
    (void)ws_size; (void)n_in; (void)out_size;

    // --- one-time prep ---
    fcvt_kernel<<<4096, 256, 0, stream>>>(
        (const float4*)features, (uint2*)fbf, (long long)N0 * 32);
    prep_wt_kernel<<<8, 256, 0, stream>>>(convW, WThi, WTlo, 128);
    fuse_fc_kernel<<<8, 256, 0, stream>>>(convW, convb, fcW, fcb, Wf, bfb);
    prep_wt_kernel<<<8, 256, 0, stream>>>(Wf, WfThi, WfTlo, 64);

    // --- bucketed CSR build (no global atomics) ---
    bcount_kernel<<<nblk0, 256, 0, stream>>>(dst0, E0, nb0, cnt + cO0);
    bcount_kernel<<<nblk1, 256, 0, stream>>>(dst1, E1, nb1, cnt + cO1);
    bcount_kernel<<<nblk2, 256, 0, stream>>>(dst2, E2, nb2, cnt + cO2);
    bscan_kernel<<<1, 512, 0, stream>>>(cnt, bo, rowptr3,
        nb0, nb1, nb2, nblk0, nblk1, nblk2, cO0, cO1, cO2, N1, N2, N3, r1, r2);
    brebase_kernel<<<(TB + 255) / 256, 256, 0, stream>>>(bo, cnt,
        nb0, nb1, nb2, nblk0, nblk1, nblk2, cO0, cO1, cO2);
    bscatter_kernel<<<nblk0, 256, 0, stream>>>(src0, dst0, E0, nb0, cnt + cO0, pairs);
    bscatter_kernel<<<nblk1, 256, 0, stream>>>(src1, dst1, E1, nb1, cnt + cO1, pairs + E0);
    bscatter_kernel<<<nblk2, 256, 0, stream>>>(src2, dst2, E2, nb2, cnt + cO2, pairs + E0 + E1);
    bfill_kernel<<<TB, 256, 0, stream>>>(bo, pairs, elist3, rowptr3,
        nb0, nb1, nb2, N1, N2, N3, E0, E1, r1, r2);

    // --- batched type bucketing (h-independent) ---
    hipMemsetAsync(tcnt, 0, 24 * 4, stream);
    int nblkT = (totalN + 255) / 256;
    count3_kernel<<<nblkT, 256, 0, stream>>>(types1, types2, types3, N1, N2, N3, tcnt);
    scan_types3_kernel<<<1, 64, 0, stream>>>(tcnt, boff, tcur);
    order3_kernel<<<nblkT, 256, 0, stream>>>(
        types1, types2, types3, N1, N2, N3, tcur, order3, no1, no2);

    // fold-in keys
    uint32_t fk1a, fk1b, fk2a, fk2b;
    tf2x32(0u, 42u, 0u, 1u, &fk1a, &fk1b);
    tf2x32(0u, 42u, 0u, 2u, &fk2a, &fk2b);

    // --- layer 0 ---
    aggregate_kernel<<<(N1 + 3) / 4, 256, 0, stream>>>(
        fbf, rowptr3, elist3, aggHi, aggLo, N1);
    mfma_gemm_kernel<128, true, true, true><<<dim3((N1 + 127) / 128, 8), 512, 0, stream>>>(
        aggHi, aggLo, order3, boff, WThi, WTlo, convb, hbf, fk1a, fk1b);

    // --- layer 1 ---
    aggregate_kernel<<<(N2 + 3) / 4, 256, 0, stream>>>(
        hbf, rowptr3 + r1, elist3 + E0, aggHi, aggLo, N2);
    mfma_gemm_kernel<128, true, true, true><<<dim3((N2 + 127) / 128, 8), 512, 0, stream>>>(
        aggHi, aggLo, order3 + no1, boff + 9, WThi, WTlo, convb, hbf, fk2a, fk2b);

    // --- layer 2 (fc folded, f32 out) ---
    aggregate_kernel<<<(N3 + 3) / 4, 256, 0, stream>>>(
        hbf, rowptr3 + r2, elist3 + E0 + E1, aggHi, aggLo, N3);
    mfma_gemm_kernel<64, false, false, false><<<dim3((N3 + 127) / 128, 8), 512, 0, stream>>>(
        aggHi, aggLo, order3 + no2, boff + 18, WfThi, WfTlo, bfb, d_out, 0u, 0u);
}

// Round 7
// 739.612 us; speedup vs baseline: 10.8420x; 1.0688x over previous
//
#include <hip/hip_runtime.h>
#include <cstdint>
#include <cstddef>

// ---------------------------------------------------------------------------
// JAX threefry2x32 (20 rounds). fold_in(key(42), i) = threefry((0,42),(0,i))
// partitionable 32-bit random_bits: bits = o0 ^ o1 (XOR-fold)   [validated r2]
// uniform: u = bitcast((bits>>9)|0x3f800000) - 1.0f ; keep iff u < 0.9f
// ---------------------------------------------------------------------------
__host__ __device__ inline void tf2x32(uint32_t k0, uint32_t k1,
                                       uint32_t x0, uint32_t x1,
                                       uint32_t* o0, uint32_t* o1)
{
    uint32_t ks2 = k0 ^ k1 ^ 0x1BD11BDAu;
    x0 += k0; x1 += k1;
#define TF_R(r) do { x0 += x1; x1 = (x1 << (r)) | (x1 >> (32 - (r))); x1 ^= x0; } while (0)
    TF_R(13); TF_R(15); TF_R(26); TF_R(6);
    x0 += k1;  x1 += ks2 + 1u;
    TF_R(17); TF_R(29); TF_R(16); TF_R(24);
    x0 += ks2; x1 += k0 + 2u;
    TF_R(13); TF_R(15); TF_R(26); TF_R(6);
    x0 += k0;  x1 += k1 + 3u;
    TF_R(17); TF_R(29); TF_R(16); TF_R(24);
    x0 += k1;  x1 += ks2 + 4u;
    TF_R(13); TF_R(15); TF_R(26); TF_R(6);
    x0 += ks2; x1 += k0 + 5u;
#undef TF_R
    *o0 = x0; *o1 = x1;
}

__device__ inline float drop_scale(uint32_t fk0, uint32_t fk1, uint32_t idx)
{
    uint32_t o0, o1;
    tf2x32(fk0, fk1, 0u, idx, &o0, &o1);
    uint32_t bits = o0 ^ o1;
    float u = __uint_as_float((bits >> 9) | 0x3f800000u) - 1.0f;
    return (u < 0.9f) ? (1.0f / 0.9f) : 0.0f;
}

// bf16 helpers (round-to-nearest-even)
__device__ inline ushort bf16_rn(float f)
{
    uint32_t u = __float_as_uint(f);
    u += 0x7fffu + ((u >> 16) & 1u);
    return (ushort)(u >> 16);
}
__device__ inline float bf16_f(ushort h) { return __uint_as_float(((uint32_t)h) << 16); }
__device__ inline uint32_t pack2bf(float a, float b)
{
    return (uint32_t)bf16_rn(a) | ((uint32_t)bf16_rn(b) << 16);
}
__device__ inline float bflo(uint32_t u) { return __uint_as_float(u << 16); }
__device__ inline float bfhi(uint32_t u) { return __uint_as_float(u & 0xffff0000u); }

typedef __attribute__((ext_vector_type(8))) short bf16x8;
typedef __attribute__((ext_vector_type(4))) float f32x4;

// ---------------------------------------------------------------------------
// features f32 -> packed bf16x2 (one-time per call, streaming)
// ---------------------------------------------------------------------------
__global__ __launch_bounds__(256) void fcvt_kernel(
    const float4* __restrict__ in, uint2* __restrict__ out, long long n4)
{
    long long stride = (long long)gridDim.x * 256;
    for (long long i = blockIdx.x * 256LL + threadIdx.x; i < n4; i += stride) {
        float4 v = in[i];
        out[i] = make_uint2(pack2bf(v.x, v.y), pack2bf(v.z, v.w));
    }
}

// ---------------------------------------------------------------------------
// Bucketed CSR build. Bucket = dst>>10 (1024 nodes). No global atomics.
// pairs entry: (dstLocal << 22) | src   (src < 2^22, dstLocal < 1024)
// ---------------------------------------------------------------------------
#define EPB 4096   // edges per block in count/scatter passes

// pass A: per-block bucket counts -> cnt[blk][NB]; blockIdx.y = layer
__global__ __launch_bounds__(256) void bcount3_kernel(
    const int* __restrict__ d0, const int* __restrict__ d1, const int* __restrict__ d2,
    int E0, int E1, int E2, int nb0, int nb1, int nb2,
    int nblk0, int nblk1, int nblk2, int cO0, int cO1, int cO2,
    uint32_t* __restrict__ cnt)
{
    int L = blockIdx.y;
    const int* dst = L == 0 ? d0 : (L == 1 ? d1 : d2);
    int E  = L == 0 ? E0 : (L == 1 ? E1 : E2);
    int NB = L == 0 ? nb0 : (L == 1 ? nb1 : nb2);
    int nblk = L == 0 ? nblk0 : (L == 1 ? nblk1 : nblk2);
    int cO = L == 0 ? cO0 : (L == 1 ? cO1 : cO2);
    if ((int)blockIdx.x >= nblk) return;

    __shared__ uint32_t lh[256];
    int tid = threadIdx.x;
    lh[tid] = 0;
    __syncthreads();
    int base = blockIdx.x * EPB;
    for (int i = tid; i < EPB; i += 256) {
        int e = base + i;
        if (e < E) atomicAdd(&lh[((uint32_t)dst[e]) >> 10], 1u);
    }
    __syncthreads();
    uint32_t* row = cnt + cO + (size_t)blockIdx.x * NB;
    if (tid < NB) row[tid] = lh[tid];
}

// pass S1+S2: bucket totals + per-layer exclusive scan -> bo[]
__global__ __launch_bounds__(512) void bscan_kernel(
    const uint32_t* __restrict__ cnt, uint32_t* __restrict__ bo,
    uint32_t* __restrict__ rowptr3,
    int nb0, int nb1, int nb2, int nblk0, int nblk1, int nblk2,
    int cO0, int cO1, int cO2, int N1, int N2, int N3, int r1, int r2)
{
    __shared__ uint32_t tot[344];
    __shared__ uint32_t bol[348];
    int t = threadIdx.x;
    int TB = nb0 + nb1 + nb2;
    if (t < TB) {
        int lb, nblk, cO, NB;
        if (t < nb0) { lb = t; nblk = nblk0; cO = cO0; NB = nb0; }
        else if (t < nb0 + nb1) { lb = t - nb0; nblk = nblk1; cO = cO1; NB = nb1; }
        else { lb = t - nb0 - nb1; nblk = nblk2; cO = cO2; NB = nb2; }
        uint32_t s = 0;
        for (int b = 0; b < nblk; ++b) s += cnt[cO + (size_t)b * NB + lb];
        tot[t] = s;
    }
    __syncthreads();
    if (t < 3) {
        int nb = t == 0 ? nb0 : (t == 1 ? nb1 : nb2);
        int g0 = t == 0 ? 0 : (t == 1 ? nb0 : nb0 + nb1);
        int gi0 = g0 + t;
        uint32_t run = 0;
        for (int i = 0; i < nb; ++i) { bol[gi0 + i] = run; run += tot[g0 + i]; }
        bol[gi0 + nb] = run;
        int rp = t == 0 ? 0 : (t == 1 ? r1 : r2);
        int N = t == 0 ? N1 : (t == 1 ? N2 : N3);
        rowptr3[rp + N] = run;
    }
    __syncthreads();
    for (int i = t; i < TB + 3; i += 512) bo[i] = bol[i];
}

// pass S3: rewrite cnt columns into running per-(block,bucket) bases
__global__ __launch_bounds__(256) void brebase_kernel(
    const uint32_t* __restrict__ bo, uint32_t* __restrict__ cnt,
    int nb0, int nb1, int nb2, int nblk0, int nblk1, int nblk2,
    int cO0, int cO1, int cO2)
{
    int t = blockIdx.x * 256 + threadIdx.x;
    int TB = nb0 + nb1 + nb2;
    if (t >= TB) return;
    int layer, lb, nblk, cO, NB;
    if (t < nb0) { layer = 0; lb = t; nblk = nblk0; cO = cO0; NB = nb0; }
    else if (t < nb0 + nb1) { layer = 1; lb = t - nb0; nblk = nblk1; cO = cO1; NB = nb1; }
    else { layer = 2; lb = t - nb0 - nb1; nblk = nblk2; cO = cO2; NB = nb2; }
    uint32_t base = bo[t + layer];
    for (int b = 0; b < nblk; ++b) {
        size_t ix = cO + (size_t)b * NB + lb;
        uint32_t old = cnt[ix]; cnt[ix] = base; base += old;
    }
}

// pass B: scatter edges into bucket-grouped pairs; blockIdx.y = layer
__global__ __launch_bounds__(256) void bscatter3_kernel(
    const int* __restrict__ s0, const int* __restrict__ d0,
    const int* __restrict__ s1, const int* __restrict__ d1,
    const int* __restrict__ s2, const int* __restrict__ d2,
    int E0, int E1, int E2, int nb0, int nb1, int nb2,
    int nblk0, int nblk1, int nblk2, int cO0, int cO1, int cO2,
    const uint32_t* __restrict__ cnt, uint32_t* __restrict__ pairs)
{
    int L = blockIdx.y;
    const int* src = L == 0 ? s0 : (L == 1 ? s1 : s2);
    const int* dst = L == 0 ? d0 : (L == 1 ? d1 : d2);
    int E  = L == 0 ? E0 : (L == 1 ? E1 : E2);
    int NB = L == 0 ? nb0 : (L == 1 ? nb1 : nb2);
    int nblk = L == 0 ? nblk0 : (L == 1 ? nblk1 : nblk2);
    int cO = L == 0 ? cO0 : (L == 1 ? cO1 : cO2);
    uint32_t* pr = pairs + (L == 0 ? 0 : (L == 1 ? E0 : E0 + E1));
    if ((int)blockIdx.x >= nblk) return;

    __shared__ uint32_t rank[256];
    int tid = threadIdx.x;
    rank[tid] = 0;
    __syncthreads();
    const uint32_t* basep = cnt + cO + (size_t)blockIdx.x * NB;
    int base = blockIdx.x * EPB;
    for (int i = tid; i < EPB; i += 256) {
        int e = base + i;
        if (e < E) {
            uint32_t d = (uint32_t)dst[e];
            uint32_t bk = d >> 10;
            uint32_t r = atomicAdd(&rank[bk], 1u);
            uint32_t pos = basep[bk] + r;
            pr[pos] = ((d & 1023u) << 22) | (uint32_t)src[e];
        }
    }
}

// pass C: one block per bucket: LDS hist -> scan -> rowptr + fine elist fill
__global__ __launch_bounds__(256) void bfill_kernel(
    const uint32_t* __restrict__ bo, const uint32_t* __restrict__ pairs,
    int* __restrict__ elist3, uint32_t* __restrict__ rowptr3,
    int nb0, int nb1, int nb2, int N1, int N2, int N3,
    int E0, int E1, int r1, int r2)
{
    __shared__ uint32_t hist[1024];
    __shared__ uint32_t cur[1024];
    __shared__ uint32_t psum[256];
    int g = blockIdx.x, tid = threadIdx.x;
    int layer, lb, N, Eoff, rp;
    if (g < nb0) { layer = 0; lb = g; N = N1; Eoff = 0; rp = 0; }
    else if (g < nb0 + nb1) { layer = 1; lb = g - nb0; N = N2; Eoff = E0; rp = r1; }
    else { layer = 2; lb = g - nb0 - nb1; N = N3; Eoff = E0 + E1; rp = r2; }
    uint32_t off = bo[g + layer], end = bo[g + layer + 1];
    int nodeBase = lb << 10;
    int nodesIn = N - nodeBase; if (nodesIn > 1024) nodesIn = 1024;

    #pragma unroll
    for (int i = 0; i < 4; ++i) hist[tid * 4 + i] = 0;
    __syncthreads();
    for (uint32_t e = off + tid; e < end; e += 256)
        atomicAdd(&hist[pairs[Eoff + e] >> 22], 1u);
    __syncthreads();

    uint32_t x[4]; uint32_t s = 0;
    #pragma unroll
    for (int i = 0; i < 4; ++i) { x[i] = hist[tid * 4 + i]; s += x[i]; }
    psum[tid] = s; __syncthreads();
    uint32_t inc = s;
    #pragma unroll
    for (int o = 1; o < 256; o <<= 1) {
        uint32_t y = (tid >= o) ? psum[tid - o] : 0u;
        __syncthreads();
        inc += y; psum[tid] = inc;
        __syncthreads();
    }
    uint32_t run = off + inc - s;
    #pragma unroll
    for (int i = 0; i < 4; ++i) { cur[tid * 4 + i] = run; run += x[i]; }
    __syncthreads();

    for (int i = tid; i < nodesIn; i += 256)
        rowptr3[rp + nodeBase + i] = cur[i];
    __syncthreads();

    for (uint32_t e = off + tid; e < end; e += 256) {
        uint32_t pk = pairs[Eoff + e];
        uint32_t pos = atomicAdd(&cur[pk >> 22], 1u);
        elist3[Eoff + pos] = (int)(pk & 0x3FFFFFu);
    }
}

// ---------------------------------------------------------------------------
// Batched type bucketing; order3 layout PADDED: each type bin rounded up to
// a multiple of 128, pad slots = -1 (GEMM tiles never span types).
// ---------------------------------------------------------------------------
__global__ __launch_bounds__(256) void count3_kernel(
    const int* __restrict__ t0, const int* __restrict__ t1, const int* __restrict__ t2,
    int n0, int n1, int n2, uint32_t* __restrict__ tcnt)
{
    __shared__ uint32_t lh[24];
    int tid = threadIdx.x;
    if (tid < 24) lh[tid] = 0;
    __syncthreads();
    int i = blockIdx.x * 256 + tid;
    if (i < n0) atomicAdd(&lh[t0[i]], 1u);
    else if (i < n0 + n1) atomicAdd(&lh[8 + t1[i - n0]], 1u);
    else if (i < n0 + n1 + n2) atomicAdd(&lh[16 + t2[i - n0 - n1]], 1u);
    __syncthreads();
    if (tid < 24 && lh[tid]) atomicAdd(&tcnt[tid], lh[tid]);
}

// padded offsets (boff, 9/layer), tcur init, and -1 pad fill of order3
__global__ __launch_bounds__(256) void scan_types3_kernel(
    const uint32_t* __restrict__ tcnt, int* __restrict__ boff,
    uint32_t* __restrict__ tcur, int* __restrict__ order3, int no1p, int no2p)
{
    __shared__ int pB[27];
    __shared__ int cnts[24];
    int tid = threadIdx.x;
    if (tid == 0) {
        for (int L = 0; L < 3; ++L) {
            int a = 0;
            for (int t = 0; t < 8; ++t) {
                pB[L * 9 + t] = a;
                int c = (int)tcnt[L * 8 + t];
                cnts[L * 8 + t] = c;
                tcur[L * 8 + t] = (uint32_t)a;
                a += (c + 127) & ~127;
            }
            pB[L * 9 + 8] = a;
        }
    }
    __syncthreads();
    if (tid < 27) boff[tid] = pB[tid];
    if (tid < 24) {
        int L = tid >> 3, t = tid & 7;
        int noff = L == 0 ? 0 : (L == 1 ? no1p : no2p);
        int s = pB[L * 9 + t] + cnts[tid];
        int e2 = pB[L * 9 + t + 1];
        for (int k = s; k < e2; ++k) order3[noff + k] = -1;
    }
}

__global__ __launch_bounds__(256) void order3_kernel(
    const int* __restrict__ t0, const int* __restrict__ t1, const int* __restrict__ t2,
    int n0, int n1, int n2, uint32_t* __restrict__ tcur,
    int* __restrict__ order3, int no1p, int no2p)
{
    __shared__ uint32_t lh[24], lbase[24];
    int tid = threadIdx.x;
    if (tid < 24) lh[tid] = 0;
    __syncthreads();
    int i = blockIdx.x * 256 + tid;
    int slot = -1, idx = 0; uint32_t r = 0;
    if (i < n0) { idx = i; slot = t0[idx]; }
    else if (i < n0 + n1) { idx = i - n0; slot = 8 + t1[idx]; }
    else if (i < n0 + n1 + n2) { idx = i - n0 - n1; slot = 16 + t2[idx]; }
    if (slot >= 0) r = atomicAdd(&lh[slot], 1u);
    __syncthreads();
    if (tid < 24 && lh[tid]) lbase[tid] = atomicAdd(&tcur[tid], lh[tid]);
    __syncthreads();
    if (slot >= 0) {
        int noff = slot < 8 ? 0 : (slot < 16 ? no1p : no2p);
        order3[noff + lbase[slot] + r] = idx;
    }
}

// ---------------------------------------------------------------------------
// Gather-aggregate: 2 nodes per wave, fused 4+4-unrolled loops -> 8
// outstanding gathers (latency-bound fix). f32 accumulate; bf16 hi/lo out.
// ---------------------------------------------------------------------------
__global__ __launch_bounds__(256) void aggregate_kernel(
    const uint32_t* __restrict__ hbf, const uint32_t* __restrict__ rowptr,
    const int* __restrict__ elist, uint32_t* __restrict__ agghi,
    uint32_t* __restrict__ agglo, int nout)
{
    int wid = threadIdx.x >> 6, lane = threadIdx.x & 63;
    int n0 = blockIdx.x * 8 + wid * 2;
    if (n0 >= nout) return;
    int n1 = n0 + 1;
    bool v1 = (n1 < nout);
    uint32_t b0 = rowptr[n0], e0 = rowptr[n0 + 1];
    uint32_t b1 = v1 ? rowptr[n1] : 0u, e1 = v1 ? rowptr[n1 + 1] : 0u;
    const uint32_t* base = hbf + lane;
    float a0x = 0.f, a0y = 0.f, a1x = 0.f, a1y = 0.f;
    uint32_t i0 = b0, i1 = b1;

    while (i0 + 4 <= e0 && i1 + 4 <= e1) {
        int s0 = elist[i0], s1 = elist[i0 + 1], s2 = elist[i0 + 2], s3 = elist[i0 + 3];
        int t0 = elist[i1], t1 = elist[i1 + 1], t2 = elist[i1 + 2], t3 = elist[i1 + 3];
        uint32_t u0 = base[(size_t)s0 * 64], u1 = base[(size_t)s1 * 64];
        uint32_t u2 = base[(size_t)s2 * 64], u3 = base[(size_t)s3 * 64];
        uint32_t w0 = base[(size_t)t0 * 64], w1 = base[(size_t)t1 * 64];
        uint32_t w2 = base[(size_t)t2 * 64], w3 = base[(size_t)t3 * 64];
        a0x += (bflo(u0) + bflo(u1)) + (bflo(u2) + bflo(u3));
        a0y += (bfhi(u0) + bfhi(u1)) + (bfhi(u2) + bfhi(u3));
        a1x += (bflo(w0) + bflo(w1)) + (bflo(w2) + bflo(w3));
        a1y += (bfhi(w0) + bfhi(w1)) + (bfhi(w2) + bfhi(w3));
        i0 += 4; i1 += 4;
    }
    while (i0 + 4 <= e0) {
        int s0 = elist[i0], s1 = elist[i0 + 1], s2 = elist[i0 + 2], s3 = elist[i0 + 3];
        uint32_t u0 = base[(size_t)s0 * 64], u1 = base[(size_t)s1 * 64];
        uint32_t u2 = base[(size_t)s2 * 64], u3 = base[(size_t)s3 * 64];
        a0x += (bflo(u0) + bflo(u1)) + (bflo(u2) + bflo(u3));
        a0y += (bfhi(u0) + bfhi(u1)) + (bfhi(u2) + bfhi(u3));
        i0 += 4;
    }
    while (i1 + 4 <= e1) {
        int t0 = elist[i1], t1 = elist[i1 + 1], t2 = elist[i1 + 2], t3 = elist[i1 + 3];
        uint32_t w0 = base[(size_t)t0 * 64], w1 = base[(size_t)t1 * 64];
        uint32_t w2 = base[(size_t)t2 * 64], w3 = base[(size_t)t3 * 64];
        a1x += (bflo(w0) + bflo(w1)) + (bflo(w2) + bflo(w3));
        a1y += (bfhi(w0) + bfhi(w1)) + (bfhi(w2) + bfhi(w3));
        i1 += 4;
    }
    for (; i0 < e0; ++i0) {
        uint32_t u = base[(size_t)elist[i0] * 64];
        a0x += bflo(u); a0y += bfhi(u);
    }
    for (; i1 < e1; ++i1) {
        uint32_t w = base[(size_t)elist[i1] * 64];
        a1x += bflo(w); a1y += bfhi(w);
    }

    float sc0 = 1.0f / fmaxf((float)(e0 - b0), 1.0f);
    a0x *= sc0; a0y *= sc0;
    ushort hx = bf16_rn(a0x); ushort lx = bf16_rn(a0x - bf16_f(hx));
    ushort hy = bf16_rn(a0y); ushort ly = bf16_rn(a0y - bf16_f(hy));
    agghi[(size_t)n0 * 64 + lane] = (uint32_t)hx | ((uint32_t)hy << 16);
    agglo[(size_t)n0 * 64 + lane] = (uint32_t)lx | ((uint32_t)ly << 16);
    if (v1) {
        float sc1 = 1.0f / fmaxf((float)(e1 - b1), 1.0f);
        a1x *= sc1; a1y *= sc1;
        ushort hx1 = bf16_rn(a1x); ushort lx1 = bf16_rn(a1x - bf16_f(hx1));
        ushort hy1 = bf16_rn(a1y); ushort ly1 = bf16_rn(a1y - bf16_f(hy1));
        agghi[(size_t)n1 * 64 + lane] = (uint32_t)hx1 | ((uint32_t)hy1 << 16);
        agglo[(size_t)n1 * 64 + lane] = (uint32_t)lx1 | ((uint32_t)ly1 << 16);
    }
}

// ---------------------------------------------------------------------------
// Weight prep: src f32 [8][128][C] (k-major) -> dst bf16 hi/lo [8][C][128]
// transposed + XOR-swizzled: chunk' = (k>>3) ^ (c&15).
// ---------------------------------------------------------------------------
__global__ __launch_bounds__(256) void prep_wt_kernel(
    const float* __restrict__ src8, ushort* __restrict__ dsthi,
    ushort* __restrict__ dstlo, int C)
{
    int t = blockIdx.x;
    const float* S = src8 + (size_t)t * 128 * C;
    ushort* DH = dsthi + (size_t)t * C * 128;
    ushort* DL = dstlo + (size_t)t * C * 128;
    for (int idx = threadIdx.x; idx < 128 * C; idx += 256) {
        int k = idx / C, c = idx % C;
        float v = S[(size_t)k * C + c];
        ushort hi = bf16_rn(v);
        ushort lo = bf16_rn(v - bf16_f(hi));
        int pos = c * 128 + ((((k >> 3) ^ (c & 15)) << 3) | (k & 7));
        DH[pos] = hi; DL[pos] = lo;
    }
}

// ---------------------------------------------------------------------------
// MFMA GEMM (split-bf16): out[n] = [relu](agg[n] @ W[t] + b[t]) [* dropout]
// 1-D grid over PADDED tiles; block derives its type via monotone search.
// ---------------------------------------------------------------------------
template<int DOUT, bool RELU, bool DROP, bool OUTBF>
__global__ __launch_bounds__(512) void mfma_gemm_kernel(
    const uint32_t* __restrict__ agghi, const uint32_t* __restrict__ agglo,
    const int* __restrict__ order, const int* __restrict__ off,
    const ushort* __restrict__ WThi, const ushort* __restrict__ WTlo,
    const float* __restrict__ bias8, void* __restrict__ houtv,
    uint32_t fk0, uint32_t fk1)
{
    __shared__ ushort AH[128 * 128];
    __shared__ ushort AL[128 * 128];
    __shared__ ushort WH[DOUT * 128];
    __shared__ ushort WL[DOUT * 128];
    __shared__ int ND[128];

    int b0 = blockIdx.x * 128;
    if (b0 >= off[8]) return;
    int t = 0;
    #pragma unroll
    for (int u = 1; u < 8; ++u) if (b0 >= off[u]) ++t;
    int tid = threadIdx.x;

    if (tid < 128) ND[tid] = order[b0 + tid];
    __syncthreads();

    // stage W (pre-transposed, pre-swizzled -> straight copy)
    {
        const float4* sh = (const float4*)(WThi + (size_t)t * DOUT * 128);
        const float4* sl = (const float4*)(WTlo + (size_t)t * DOUT * 128);
        float4* dh = (float4*)WH; float4* dl = (float4*)WL;
        #pragma unroll
        for (int it = 0; it < DOUT * 16 / 512; ++it) {
            int c = it * 512 + tid;
            dh[c] = sh[c]; dl[c] = sl[c];
        }
    }
    // stage A: gather rows via ND, swizzle chunk by tile-local (row&15)
    {
        const float4* gh = (const float4*)agghi;
        const float4* gl = (const float4*)agglo;
        float4* dh = (float4*)AH; float4* dl = (float4*)AL;
        #pragma unroll
        for (int it = 0; it < 4; ++it) {
            int g = it * 512 + tid;
            int row = g >> 4, ch = g & 15;
            int nd = ND[row];
            float4 vh = make_float4(0.f, 0.f, 0.f, 0.f);
            float4 vl = make_float4(0.f, 0.f, 0.f, 0.f);
            if (nd >= 0) {
                vh = gh[(size_t)nd * 16 + ch];
                vl = gl[(size_t)nd * 16 + ch];
            }
            int dch = ch ^ (row & 15);
            dh[row * 16 + dch] = vh;
            dl[row * 16 + dch] = vl;
        }
    }
    __syncthreads();

    int wid = tid >> 6, lane = tid & 63;
    int r15 = lane & 15, q = lane >> 4;
    constexpr int NF = DOUT / 16;
    f32x4 acc[NF];
    #pragma unroll
    for (int i = 0; i < NF; ++i) acc[i] = (f32x4){0.f, 0.f, 0.f, 0.f};

    int arow = wid * 16 + r15;
    const bf16x8* AHp = (const bf16x8*)AH;
    const bf16x8* ALp = (const bf16x8*)AL;
    const bf16x8* WHp = (const bf16x8*)WH;
    const bf16x8* WLp = (const bf16x8*)WL;

    #pragma unroll
    for (int ks = 0; ks < 4; ++ks) {
        int sch = (q + ks * 4) ^ r15;
        bf16x8 ah = AHp[arow * 16 + sch];
        bf16x8 al = ALp[arow * 16 + sch];
        #pragma unroll
        for (int nf = 0; nf < NF; ++nf) {
            int col = nf * 16 + r15;
            bf16x8 bh = WHp[col * 16 + sch];
            bf16x8 bl = WLp[col * 16 + sch];
            acc[nf] = __builtin_amdgcn_mfma_f32_16x16x32_bf16(ah, bh, acc[nf], 0, 0, 0);
            acc[nf] = __builtin_amdgcn_mfma_f32_16x16x32_bf16(ah, bl, acc[nf], 0, 0, 0);
            acc[nf] = __builtin_amdgcn_mfma_f32_16x16x32_bf16(al, bh, acc[nf], 0, 0, 0);
        }
    }

    // epilogue: C/D row = wid*16 + q*4 + r, col = nf*16 + r15
    int ndr[4];
    #pragma unroll
    for (int r = 0; r < 4; ++r) ndr[r] = ND[wid * 16 + q * 4 + r];
    const float* bptr = bias8 + (size_t)t * DOUT;

    #pragma unroll
    for (int nf = 0; nf < NF; ++nf) {
        int col = nf * 16 + r15;
        float bv = bptr[col];
        float vr[4];
        #pragma unroll
        for (int r = 0; r < 4; ++r) {
            float v = acc[nf][r] + bv;
            if (RELU) v = fmaxf(v, 0.f);
            if (DROP) {
                int nd = ndr[r] < 0 ? 0 : ndr[r];
                v *= drop_scale(fk0, fk1, (uint32_t)nd * 128u + (uint32_t)col);
            }
            vr[r] = v;
        }
        if (OUTBF) {
            uint32_t* hb = (uint32_t*)houtv;
            #pragma unroll
            for (int r = 0; r < 4; ++r) {
                float w = __shfl_xor(vr[r], 1, 64);
                if ((lane & 1) == 0 && ndr[r] >= 0)
                    hb[(size_t)ndr[r] * (DOUT / 2) + (col >> 1)] = pack2bf(vr[r], w);
            }
        } else {
            float* ho = (float*)houtv;
            #pragma unroll
            for (int r = 0; r < 4; ++r)
                if (ndr[r] >= 0) ho[(size_t)ndr[r] * DOUT + col] = vr[r];
        }
    }
}

// ---------------------------------------------------------------------------
// fc fusion: Wf[t] = W[t] @ fcW (128x64 f32), bf[t] = b[t] @ fcW + fcb
// ---------------------------------------------------------------------------
__global__ __launch_bounds__(256) void fuse_fc_kernel(
    const float* __restrict__ convW, const float* __restrict__ convb,
    const float* __restrict__ fcW, const float* __restrict__ fcb,
    float* __restrict__ Wf, float* __restrict__ bf)
{
    __shared__ float F[128 * 64];
    int t = blockIdx.x, tid = threadIdx.x;
    #pragma unroll
    for (int it = 0; it < 8; ++it) {
        int idx4 = (it * 256 + tid) * 4;
        *(float4*)&F[idx4] = *(const float4*)&fcW[idx4];
    }
    __syncthreads();

    int r = tid >> 1, cb = (tid & 1) * 32;
    const float* Wrow = convW + (size_t)t * 16384 + (size_t)r * 128;
    float acc[32];
    #pragma unroll
    for (int c = 0; c < 32; ++c) acc[c] = 0.f;
    for (int k = 0; k < 128; ++k) {
        float w = Wrow[k];
        #pragma unroll
        for (int c = 0; c < 32; ++c) acc[c] += w * F[k * 64 + cb + c];
    }
    float* outp = Wf + (size_t)t * 8192 + (size_t)r * 64 + cb;
    #pragma unroll
    for (int c = 0; c < 32; ++c) outp[c] = acc[c];

    if (tid < 64) {
        float a = fcb[tid];
        const float* bt = convb + (size_t)t * 128;
        for (int k = 0; k < 128; ++k) a += bt[k] * F[k * 64 + tid];
        bf[(size_t)t * 64 + tid] = a;
    }
}

// ---------------------------------------------------------------------------
extern "C" void kernel_launch(void* const* d_in, const int* in_sizes, int n_in,
                              void* d_out, int out_size, void* d_ws, size_t ws_size,
                              hipStream_t stream)
{
    const float* features = (const float*)d_in[0];
    const int*   src0 = (const int*)d_in[1];
    const int*   dst0 = (const int*)d_in[2];
    const int*   types1 = (const int*)d_in[3];
    const int*   src1 = (const int*)d_in[4];
    const int*   dst1 = (const int*)d_in[5];
    const int*   types2 = (const int*)d_in[6];
    const int*   src2 = (const int*)d_in[7];
    const int*   dst2 = (const int*)d_in[8];
    const int*   types3 = (const int*)d_in[9];
    const float* convW = (const float*)d_in[10];
    const float* convb = (const float*)d_in[11];
    const float* fcW   = (const float*)d_in[12];
    const float* fcb   = (const float*)d_in[13];

    int N0 = in_sizes[0] / 128;
    int E0 = in_sizes[1], N1 = in_sizes[3];
    int E1 = in_sizes[4], N2 = in_sizes[6];
    int E2 = in_sizes[7], N3 = in_sizes[9];
    int totalN = N1 + N2 + N3;
    int totalE = E0 + E1 + E2;
    int r1 = N1 + 1, r2 = N1 + 1 + N2 + 1;           // rowptr offsets
    int no1p = N1 + 1024, no2p = no1p + N2 + 1024;   // padded order3 offsets
    int maxN = N1 > N2 ? N1 : N2; if (N3 > maxN) maxN = N3;

    // bucket-sort geometry
    int nb0 = (N1 + 1023) >> 10, nb1 = (N2 + 1023) >> 10, nb2 = (N3 + 1023) >> 10;
    int TB = nb0 + nb1 + nb2;
    int nblk0 = (E0 + EPB - 1) / EPB, nblk1 = (E1 + EPB - 1) / EPB, nblk2 = (E2 + EPB - 1) / EPB;
    int nblkMax = nblk0 > nblk1 ? nblk0 : nblk1; if (nblk2 > nblkMax) nblkMax = nblk2;
    int cO0 = 0;
    int cO1 = cO0 + nblk0 * nb0;
    int cO2 = cO1 + nblk1 * nb1;
    int cntEntries = cO2 + nblk2 * nb2;

    char* ws = (char*)d_ws;
    size_t woff = 0;
    auto alloc = [&](size_t bytes) -> void* {
        void* p = ws + woff;
        woff = (woff + bytes + 255) & ~(size_t)255;
        return p;
    };
    uint32_t* fbf     = (uint32_t*)alloc((size_t)N0 * 64 * 4);    // packed bf16 features
    uint32_t* hbf     = fbf;                                      // alias: h after L0 agg
    uint32_t* aggHi   = (uint32_t*)alloc((size_t)maxN * 64 * 4);
    uint32_t* pairs   = aggHi;                                    // alias: dead before agg
    uint32_t* aggLo   = (uint32_t*)alloc((size_t)maxN * 64 * 4);
    uint32_t* rowptr3 = (uint32_t*)alloc((size_t)(totalN + 3) * 4);
    int*      elist3  = (int*)alloc((size_t)totalE * 4);
    int*      order3  = (int*)alloc((size_t)(totalN + 3 * 1024) * 4);
    uint32_t* cnt     = (uint32_t*)alloc((size_t)cntEntries * 4);
    uint32_t* bo      = (uint32_t*)alloc((size_t)(TB + 3) * 4);
    uint32_t* tcnt    = (uint32_t*)alloc(24 * 4);
    int*      boff    = (int*)alloc(27 * 4);
    uint32_t* tcur    = (uint32_t*)alloc(24 * 4);
    float*    Wf      = (float*)alloc((size_t)8 * 128 * 64 * 4);
    float*    bfb     = (float*)alloc((size_t)8 * 64 * 4);
    ushort*   WThi    = (ushort*)alloc((size_t)8 * 128 * 128 * 2);
    ushort*   WTlo    = (ushort*)alloc((size_t)8 * 128 * 128 * 2);
    ushort*   WfThi   = (ushort*)alloc((size_t)8 * 64 * 128 * 2);
    ushort*   WfTlo   = (ushort*)alloc((size_t)8 * 64 * 128 * 2);
    (void)ws_size; (void)n_in; (void)out_size;

    // --- one-time prep ---
    fcvt_kernel<<<4096, 256, 0, stream>>>(
        (const float4*)features, (uint2*)fbf, (long long)N0 * 32);
    prep_wt_kernel<<<8, 256, 0, stream>>>(convW, WThi, WTlo, 128);
    fuse_fc_kernel<<<8, 256, 0, stream>>>(convW, convb, fcW, fcb, Wf, bfb);
    prep_wt_kernel<<<8, 256, 0, stream>>>(Wf, WfThi, WfTlo, 64);

    // --- bucketed CSR build (no global atomics) ---
    bcount3_kernel<<<dim3(nblkMax, 3), 256, 0, stream>>>(
        dst0, dst1, dst2, E0, E1, E2, nb0, nb1, nb2,
        nblk0, nblk1, nblk2, cO0, cO1, cO2, cnt);
    bscan_kernel<<<1, 512, 0, stream>>>(cnt, bo, rowptr3,
        nb0, nb1, nb2, nblk0, nblk1, nblk2, cO0, cO1, cO2, N1, N2, N3, r1, r2);
    brebase_kernel<<<(TB + 255) / 256, 256, 0, stream>>>(bo, cnt,
        nb0, nb1, nb2, nblk0, nblk1, nblk2, cO0, cO1, cO2);
    bscatter3_kernel<<<dim3(nblkMax, 3), 256, 0, stream>>>(
        src0, dst0, src1, dst1, src2, dst2, E0, E1, E2, nb0, nb1, nb2,
        nblk0, nblk1, nblk2, cO0, cO1, cO2, cnt, pairs);
    bfill_kernel<<<TB, 256, 0, stream>>>(bo, pairs, elist3, rowptr3,
        nb0, nb1, nb2, N1, N2, N3, E0, E1, r1, r2);

    // --- batched type bucketing (padded bins) ---
    hipMemsetAsync(tcnt, 0, 24 * 4, stream);
    int nblkT = (totalN + 255) / 256;
    count3_kernel<<<nblkT, 256, 0, stream>>>(types1, types2, types3, N1, N2, N3, tcnt);
    scan_types3_kernel<<<1, 256, 0, stream>>>(tcnt, boff, tcur, order3, no1p, no2p);
    order3_kernel<<<nblkT, 256, 0, stream>>>(
        types1, types2, types3, N1, N2, N3, tcur, order3, no1p, no2p);

    // fold-in keys
    uint32_t fk1a, fk1b, fk2a, fk2b;
    tf2x32(0u, 42u, 0u, 1u, &fk1a, &fk1b);
    tf2x32(0u, 42u, 0u, 2u, &fk2a, &fk2b);

    // --- layer 0 ---
    aggregate_kernel<<<(N1 + 7) / 8, 256, 0, stream>>>(
        fbf, rowptr3, elist3, aggHi, aggLo, N1);
    mfma_gemm_kernel<128, true, true, true><<<(N1 + 127) / 128 + 8, 512, 0, stream>>>(
        aggHi, aggLo, order3, boff, WThi, WTlo, convb, hbf, fk1a, fk1b);

    // --- layer 1 ---
    aggregate_kernel<<<(N2 + 7) / 8, 256, 0, stream>>>(
        hbf, rowptr3 + r1, elist3 + E0, aggHi, aggLo, N2);
    mfma_gemm_kernel<128, true, true, true><<<(N2 + 127) / 128 + 8, 512, 0, stream>>>(
        aggHi, aggLo, order3 + no1p, boff + 9, WThi, WTlo, convb, hbf, fk2a, fk2b);

    // --- layer 2 (fc folded, f32 out) ---
    aggregate_kernel<<<(N3 + 7) / 8, 256, 0, stream>>>(
        hbf, rowptr3 + r2, elist3 + E0 + E1, aggHi, aggLo, N3);
    mfma_gemm_kernel<64, false, false, false><<<(N3 + 127) / 128 + 8, 512, 0, stream>>>(
        aggHi, aggLo, order3 + no2p, boff + 18, WfThi, WfTlo, bfb, d_out, 0u, 0u);
}

// Round 8
// 695.681 us; speedup vs baseline: 11.5266x; 1.0631x over previous
//
#include <hip/hip_runtime.h>
#include <cstdint>
#include <cstddef>

// ---------------------------------------------------------------------------
// JAX threefry2x32 (20 rounds). fold_in(key(42), i) = threefry((0,42),(0,i))
// partitionable 32-bit random_bits: bits = o0 ^ o1 (XOR-fold)   [validated r2]
// uniform: u = bitcast((bits>>9)|0x3f800000) - 1.0f ; keep iff u < 0.9f
// ---------------------------------------------------------------------------
__host__ __device__ inline void tf2x32(uint32_t k0, uint32_t k1,
                                       uint32_t x0, uint32_t x1,
                                       uint32_t* o0, uint32_t* o1)
{
    uint32_t ks2 = k0 ^ k1 ^ 0x1BD11BDAu;
    x0 += k0; x1 += k1;
#define TF_R(r) do { x0 += x1; x1 = (x1 << (r)) | (x1 >> (32 - (r))); x1 ^= x0; } while (0)
    TF_R(13); TF_R(15); TF_R(26); TF_R(6);
    x0 += k1;  x1 += ks2 + 1u;
    TF_R(17); TF_R(29); TF_R(16); TF_R(24);
    x0 += ks2; x1 += k0 + 2u;
    TF_R(13); TF_R(15); TF_R(26); TF_R(6);
    x0 += k0;  x1 += k1 + 3u;
    TF_R(17); TF_R(29); TF_R(16); TF_R(24);
    x0 += k1;  x1 += ks2 + 4u;
    TF_R(13); TF_R(15); TF_R(26); TF_R(6);
    x0 += ks2; x1 += k0 + 5u;
#undef TF_R
    *o0 = x0; *o1 = x1;
}

__device__ inline float drop_scale(uint32_t fk0, uint32_t fk1, uint32_t idx)
{
    uint32_t o0, o1;
    tf2x32(fk0, fk1, 0u, idx, &o0, &o1);
    uint32_t bits = o0 ^ o1;
    float u = __uint_as_float((bits >> 9) | 0x3f800000u) - 1.0f;
    return (u < 0.9f) ? (1.0f / 0.9f) : 0.0f;
}

// bf16 helpers (round-to-nearest-even)
__device__ inline ushort bf16_rn(float f)
{
    uint32_t u = __float_as_uint(f);
    u += 0x7fffu + ((u >> 16) & 1u);
    return (ushort)(u >> 16);
}
__device__ inline float bf16_f(ushort h) { return __uint_as_float(((uint32_t)h) << 16); }
__device__ inline uint32_t pack2bf(float a, float b)
{
    return (uint32_t)bf16_rn(a) | ((uint32_t)bf16_rn(b) << 16);
}
__device__ inline float bflo(uint32_t u) { return __uint_as_float(u << 16); }
__device__ inline float bfhi(uint32_t u) { return __uint_as_float(u & 0xffff0000u); }

typedef __attribute__((ext_vector_type(8))) short bf16x8;
typedef __attribute__((ext_vector_type(4))) float f32x4;

// ---------------------------------------------------------------------------
// features f32 -> packed bf16x2 (one-time per call, streaming)
// ---------------------------------------------------------------------------
__global__ __launch_bounds__(256) void fcvt_kernel(
    const float4* __restrict__ in, uint2* __restrict__ out, long long n4)
{
    long long stride = (long long)gridDim.x * 256;
    for (long long i = blockIdx.x * 256LL + threadIdx.x; i < n4; i += stride) {
        float4 v = in[i];
        out[i] = make_uint2(pack2bf(v.x, v.y), pack2bf(v.z, v.w));
    }
}

// ---------------------------------------------------------------------------
// Bucketed CSR build. Bucket = dst>>10 (1024 nodes). No global atomics.
// pairs entry: (dstLocal << 22) | src   (src < 2^22, dstLocal < 1024)
// ---------------------------------------------------------------------------
#define EPB 4096   // edges per block in count/scatter passes

// pass A: per-block bucket counts -> cnt[blk][NB]; blockIdx.y = layer
__global__ __launch_bounds__(256) void bcount3_kernel(
    const int* __restrict__ d0, const int* __restrict__ d1, const int* __restrict__ d2,
    int E0, int E1, int E2, int nb0, int nb1, int nb2,
    int nblk0, int nblk1, int nblk2, int cO0, int cO1, int cO2,
    uint32_t* __restrict__ cnt)
{
    int L = blockIdx.y;
    const int* dst = L == 0 ? d0 : (L == 1 ? d1 : d2);
    int E  = L == 0 ? E0 : (L == 1 ? E1 : E2);
    int NB = L == 0 ? nb0 : (L == 1 ? nb1 : nb2);
    int nblk = L == 0 ? nblk0 : (L == 1 ? nblk1 : nblk2);
    int cO = L == 0 ? cO0 : (L == 1 ? cO1 : cO2);
    if ((int)blockIdx.x >= nblk) return;

    __shared__ uint32_t lh[256];
    int tid = threadIdx.x;
    lh[tid] = 0;
    __syncthreads();
    int base = blockIdx.x * EPB;
    for (int i = tid; i < EPB; i += 256) {
        int e = base + i;
        if (e < E) atomicAdd(&lh[((uint32_t)dst[e]) >> 10], 1u);
    }
    __syncthreads();
    uint32_t* row = cnt + cO + (size_t)blockIdx.x * NB;
    if (tid < NB) row[tid] = lh[tid];
}

// pass S1+S2: bucket totals + per-layer exclusive scan -> bo[]
__global__ __launch_bounds__(512) void bscan_kernel(
    const uint32_t* __restrict__ cnt, uint32_t* __restrict__ bo,
    uint32_t* __restrict__ rowptr3,
    int nb0, int nb1, int nb2, int nblk0, int nblk1, int nblk2,
    int cO0, int cO1, int cO2, int N1, int N2, int N3, int r1, int r2)
{
    __shared__ uint32_t tot[344];
    __shared__ uint32_t bol[348];
    int t = threadIdx.x;
    int TB = nb0 + nb1 + nb2;
    if (t < TB) {
        int lb, nblk, cO, NB;
        if (t < nb0) { lb = t; nblk = nblk0; cO = cO0; NB = nb0; }
        else if (t < nb0 + nb1) { lb = t - nb0; nblk = nblk1; cO = cO1; NB = nb1; }
        else { lb = t - nb0 - nb1; nblk = nblk2; cO = cO2; NB = nb2; }
        uint32_t s = 0;
        for (int b = 0; b < nblk; ++b) s += cnt[cO + (size_t)b * NB + lb];
        tot[t] = s;
    }
    __syncthreads();
    if (t < 3) {
        int nb = t == 0 ? nb0 : (t == 1 ? nb1 : nb2);
        int g0 = t == 0 ? 0 : (t == 1 ? nb0 : nb0 + nb1);
        int gi0 = g0 + t;
        uint32_t run = 0;
        for (int i = 0; i < nb; ++i) { bol[gi0 + i] = run; run += tot[g0 + i]; }
        bol[gi0 + nb] = run;
        int rp = t == 0 ? 0 : (t == 1 ? r1 : r2);
        int N = t == 0 ? N1 : (t == 1 ? N2 : N3);
        rowptr3[rp + N] = run;
    }
    __syncthreads();
    for (int i = t; i < TB + 3; i += 512) bo[i] = bol[i];
}

// pass S3: rewrite cnt columns into running per-(block,bucket) bases
__global__ __launch_bounds__(256) void brebase_kernel(
    const uint32_t* __restrict__ bo, uint32_t* __restrict__ cnt,
    int nb0, int nb1, int nb2, int nblk0, int nblk1, int nblk2,
    int cO0, int cO1, int cO2)
{
    int t = blockIdx.x * 256 + threadIdx.x;
    int TB = nb0 + nb1 + nb2;
    if (t >= TB) return;
    int layer, lb, nblk, cO, NB;
    if (t < nb0) { layer = 0; lb = t; nblk = nblk0; cO = cO0; NB = nb0; }
    else if (t < nb0 + nb1) { layer = 1; lb = t - nb0; nblk = nblk1; cO = cO1; NB = nb1; }
    else { layer = 2; lb = t - nb0 - nb1; nblk = nblk2; cO = cO2; NB = nb2; }
    uint32_t base = bo[t + layer];
    for (int b = 0; b < nblk; ++b) {
        size_t ix = cO + (size_t)b * NB + lb;
        uint32_t old = cnt[ix]; cnt[ix] = base; base += old;
    }
}

// pass B: scatter edges into bucket-grouped pairs; blockIdx.y = layer
__global__ __launch_bounds__(256) void bscatter3_kernel(
    const int* __restrict__ s0, const int* __restrict__ d0,
    const int* __restrict__ s1, const int* __restrict__ d1,
    const int* __restrict__ s2, const int* __restrict__ d2,
    int E0, int E1, int E2, int nb0, int nb1, int nb2,
    int nblk0, int nblk1, int nblk2, int cO0, int cO1, int cO2,
    const uint32_t* __restrict__ cnt, uint32_t* __restrict__ pairs)
{
    int L = blockIdx.y;
    const int* src = L == 0 ? s0 : (L == 1 ? s1 : s2);
    const int* dst = L == 0 ? d0 : (L == 1 ? d1 : d2);
    int E  = L == 0 ? E0 : (L == 1 ? E1 : E2);
    int NB = L == 0 ? nb0 : (L == 1 ? nb1 : nb2);
    int nblk = L == 0 ? nblk0 : (L == 1 ? nblk1 : nblk2);
    int cO = L == 0 ? cO0 : (L == 1 ? cO1 : cO2);
    uint32_t* pr = pairs + (L == 0 ? 0 : (L == 1 ? E0 : E0 + E1));
    if ((int)blockIdx.x >= nblk) return;

    __shared__ uint32_t rank[256];
    int tid = threadIdx.x;
    rank[tid] = 0;
    __syncthreads();
    const uint32_t* basep = cnt + cO + (size_t)blockIdx.x * NB;
    int base = blockIdx.x * EPB;
    for (int i = tid; i < EPB; i += 256) {
        int e = base + i;
        if (e < E) {
            uint32_t d = (uint32_t)dst[e];
            uint32_t bk = d >> 10;
            uint32_t r = atomicAdd(&rank[bk], 1u);
            uint32_t pos = basep[bk] + r;
            pr[pos] = ((d & 1023u) << 22) | (uint32_t)src[e];
        }
    }
}

// pass C: one block per bucket: LDS hist -> scan -> rowptr + fine elist fill
__global__ __launch_bounds__(256) void bfill_kernel(
    const uint32_t* __restrict__ bo, const uint32_t* __restrict__ pairs,
    int* __restrict__ elist3, uint32_t* __restrict__ rowptr3,
    int nb0, int nb1, int nb2, int N1, int N2, int N3,
    int E0, int E1, int r1, int r2)
{
    __shared__ uint32_t hist[1024];
    __shared__ uint32_t cur[1024];
    __shared__ uint32_t psum[256];
    int g = blockIdx.x, tid = threadIdx.x;
    int layer, lb, N, Eoff, rp;
    if (g < nb0) { layer = 0; lb = g; N = N1; Eoff = 0; rp = 0; }
    else if (g < nb0 + nb1) { layer = 1; lb = g - nb0; N = N2; Eoff = E0; rp = r1; }
    else { layer = 2; lb = g - nb0 - nb1; N = N3; Eoff = E0 + E1; rp = r2; }
    uint32_t off = bo[g + layer], end = bo[g + layer + 1];
    int nodeBase = lb << 10;
    int nodesIn = N - nodeBase; if (nodesIn > 1024) nodesIn = 1024;

    #pragma unroll
    for (int i = 0; i < 4; ++i) hist[tid * 4 + i] = 0;
    __syncthreads();
    for (uint32_t e = off + tid; e < end; e += 256)
        atomicAdd(&hist[pairs[Eoff + e] >> 22], 1u);
    __syncthreads();

    uint32_t x[4]; uint32_t s = 0;
    #pragma unroll
    for (int i = 0; i < 4; ++i) { x[i] = hist[tid * 4 + i]; s += x[i]; }
    psum[tid] = s; __syncthreads();
    uint32_t inc = s;
    #pragma unroll
    for (int o = 1; o < 256; o <<= 1) {
        uint32_t y = (tid >= o) ? psum[tid - o] : 0u;
        __syncthreads();
        inc += y; psum[tid] = inc;
        __syncthreads();
    }
    uint32_t run = off + inc - s;
    #pragma unroll
    for (int i = 0; i < 4; ++i) { cur[tid * 4 + i] = run; run += x[i]; }
    __syncthreads();

    for (int i = tid; i < nodesIn; i += 256)
        rowptr3[rp + nodeBase + i] = cur[i];
    __syncthreads();

    for (uint32_t e = off + tid; e < end; e += 256) {
        uint32_t pk = pairs[Eoff + e];
        uint32_t pos = atomicAdd(&cur[pk >> 22], 1u);
        elist3[Eoff + pos] = (int)(pk & 0x3FFFFFu);
    }
}

// ---------------------------------------------------------------------------
// Batched type bucketing; order3 PADDED to 128-multiples per bin (pad = -1)
// ---------------------------------------------------------------------------
__global__ __launch_bounds__(256) void count3_kernel(
    const int* __restrict__ t0, const int* __restrict__ t1, const int* __restrict__ t2,
    int n0, int n1, int n2, uint32_t* __restrict__ tcnt)
{
    __shared__ uint32_t lh[24];
    int tid = threadIdx.x;
    if (tid < 24) lh[tid] = 0;
    __syncthreads();
    int i = blockIdx.x * 256 + tid;
    if (i < n0) atomicAdd(&lh[t0[i]], 1u);
    else if (i < n0 + n1) atomicAdd(&lh[8 + t1[i - n0]], 1u);
    else if (i < n0 + n1 + n2) atomicAdd(&lh[16 + t2[i - n0 - n1]], 1u);
    __syncthreads();
    if (tid < 24 && lh[tid]) atomicAdd(&tcnt[tid], lh[tid]);
}

__global__ __launch_bounds__(256) void scan_types3_kernel(
    const uint32_t* __restrict__ tcnt, int* __restrict__ boff,
    uint32_t* __restrict__ tcur, int* __restrict__ order3, int no1p, int no2p)
{
    __shared__ int pB[27];
    __shared__ int cnts[24];
    int tid = threadIdx.x;
    if (tid == 0) {
        for (int L = 0; L < 3; ++L) {
            int a = 0;
            for (int t = 0; t < 8; ++t) {
                pB[L * 9 + t] = a;
                int c = (int)tcnt[L * 8 + t];
                cnts[L * 8 + t] = c;
                tcur[L * 8 + t] = (uint32_t)a;
                a += (c + 127) & ~127;
            }
            pB[L * 9 + 8] = a;
        }
    }
    __syncthreads();
    if (tid < 27) boff[tid] = pB[tid];
    if (tid < 24) {
        int L = tid >> 3, t = tid & 7;
        int noff = L == 0 ? 0 : (L == 1 ? no1p : no2p);
        int s = pB[L * 9 + t] + cnts[tid];
        int e2 = pB[L * 9 + t + 1];
        for (int k = s; k < e2; ++k) order3[noff + k] = -1;
    }
}

__global__ __launch_bounds__(256) void order3_kernel(
    const int* __restrict__ t0, const int* __restrict__ t1, const int* __restrict__ t2,
    int n0, int n1, int n2, uint32_t* __restrict__ tcur,
    int* __restrict__ order3, int no1p, int no2p)
{
    __shared__ uint32_t lh[24], lbase[24];
    int tid = threadIdx.x;
    if (tid < 24) lh[tid] = 0;
    __syncthreads();
    int i = blockIdx.x * 256 + tid;
    int slot = -1, idx = 0; uint32_t r = 0;
    if (i < n0) { idx = i; slot = t0[idx]; }
    else if (i < n0 + n1) { idx = i - n0; slot = 8 + t1[idx]; }
    else if (i < n0 + n1 + n2) { idx = i - n0 - n1; slot = 16 + t2[idx]; }
    if (slot >= 0) r = atomicAdd(&lh[slot], 1u);
    __syncthreads();
    if (tid < 24 && lh[tid]) lbase[tid] = atomicAdd(&tcur[tid], lh[tid]);
    __syncthreads();
    if (slot >= 0) {
        int noff = slot < 8 ? 0 : (slot < 16 ? no1p : no2p);
        order3[noff + lbase[slot] + r] = idx;
    }
}

// ---------------------------------------------------------------------------
// Gather-aggregate: 2 nodes per wave, fused 8+8-unrolled main loop -> 16
// outstanding gathers. f32 accumulate; bf16 hi/lo out.
// ---------------------------------------------------------------------------
__global__ __launch_bounds__(256) void aggregate_kernel(
    const uint32_t* __restrict__ hbf, const uint32_t* __restrict__ rowptr,
    const int* __restrict__ elist, uint32_t* __restrict__ agghi,
    uint32_t* __restrict__ agglo, int nout)
{
    int wid = threadIdx.x >> 6, lane = threadIdx.x & 63;
    int n0 = blockIdx.x * 8 + wid * 2;
    if (n0 >= nout) return;
    int n1 = n0 + 1;
    bool v1 = (n1 < nout);
    uint32_t b0 = rowptr[n0], e0 = rowptr[n0 + 1];
    uint32_t b1 = v1 ? rowptr[n1] : 0u, e1 = v1 ? rowptr[n1 + 1] : 0u;
    const uint32_t* base = hbf + lane;
    float a0x = 0.f, a0y = 0.f, a1x = 0.f, a1y = 0.f;
    uint32_t i0 = b0, i1 = b1;

    while (i0 + 8 <= e0 && i1 + 8 <= e1) {
        uint32_t u[8], w[8];
        #pragma unroll
        for (int k = 0; k < 8; ++k) u[k] = base[(size_t)elist[i0 + k] * 64];
        #pragma unroll
        for (int k = 0; k < 8; ++k) w[k] = base[(size_t)elist[i1 + k] * 64];
        #pragma unroll
        for (int k = 0; k < 8; ++k) { a0x += bflo(u[k]); a0y += bfhi(u[k]); }
        #pragma unroll
        for (int k = 0; k < 8; ++k) { a1x += bflo(w[k]); a1y += bfhi(w[k]); }
        i0 += 8; i1 += 8;
    }
    while (i0 + 4 <= e0 && i1 + 4 <= e1) {
        uint32_t u[4], w[4];
        #pragma unroll
        for (int k = 0; k < 4; ++k) u[k] = base[(size_t)elist[i0 + k] * 64];
        #pragma unroll
        for (int k = 0; k < 4; ++k) w[k] = base[(size_t)elist[i1 + k] * 64];
        #pragma unroll
        for (int k = 0; k < 4; ++k) { a0x += bflo(u[k]); a0y += bfhi(u[k]); }
        #pragma unroll
        for (int k = 0; k < 4; ++k) { a1x += bflo(w[k]); a1y += bfhi(w[k]); }
        i0 += 4; i1 += 4;
    }
    while (i0 + 4 <= e0) {
        uint32_t u[4];
        #pragma unroll
        for (int k = 0; k < 4; ++k) u[k] = base[(size_t)elist[i0 + k] * 64];
        #pragma unroll
        for (int k = 0; k < 4; ++k) { a0x += bflo(u[k]); a0y += bfhi(u[k]); }
        i0 += 4;
    }
    while (i1 + 4 <= e1) {
        uint32_t w[4];
        #pragma unroll
        for (int k = 0; k < 4; ++k) w[k] = base[(size_t)elist[i1 + k] * 64];
        #pragma unroll
        for (int k = 0; k < 4; ++k) { a1x += bflo(w[k]); a1y += bfhi(w[k]); }
        i1 += 4;
    }
    for (; i0 < e0; ++i0) {
        uint32_t u = base[(size_t)elist[i0] * 64];
        a0x += bflo(u); a0y += bfhi(u);
    }
    for (; i1 < e1; ++i1) {
        uint32_t w = base[(size_t)elist[i1] * 64];
        a1x += bflo(w); a1y += bfhi(w);
    }

    float sc0 = 1.0f / fmaxf((float)(e0 - b0), 1.0f);
    a0x *= sc0; a0y *= sc0;
    ushort hx = bf16_rn(a0x); ushort lx = bf16_rn(a0x - bf16_f(hx));
    ushort hy = bf16_rn(a0y); ushort ly = bf16_rn(a0y - bf16_f(hy));
    agghi[(size_t)n0 * 64 + lane] = (uint32_t)hx | ((uint32_t)hy << 16);
    agglo[(size_t)n0 * 64 + lane] = (uint32_t)lx | ((uint32_t)ly << 16);
    if (v1) {
        float sc1 = 1.0f / fmaxf((float)(e1 - b1), 1.0f);
        a1x *= sc1; a1y *= sc1;
        ushort hx1 = bf16_rn(a1x); ushort lx1 = bf16_rn(a1x - bf16_f(hx1));
        ushort hy1 = bf16_rn(a1y); ushort ly1 = bf16_rn(a1y - bf16_f(hy1));
        agghi[(size_t)n1 * 64 + lane] = (uint32_t)hx1 | ((uint32_t)hy1 << 16);
        agglo[(size_t)n1 * 64 + lane] = (uint32_t)lx1 | ((uint32_t)ly1 << 16);
    }
}

// ---------------------------------------------------------------------------
// Weight prep: src f32 [8][128][C] (k-major) -> dst bf16 hi/lo [8][C][128]
// transposed + XOR-swizzled: chunk' = (k>>3) ^ (c&15).
// ---------------------------------------------------------------------------
__global__ __launch_bounds__(256) void prep_wt_kernel(
    const float* __restrict__ src8, ushort* __restrict__ dsthi,
    ushort* __restrict__ dstlo, int C)
{
    int t = blockIdx.x;
    const float* S = src8 + (size_t)t * 128 * C;
    ushort* DH = dsthi + (size_t)t * C * 128;
    ushort* DL = dstlo + (size_t)t * C * 128;
    for (int idx = threadIdx.x; idx < 128 * C; idx += 256) {
        int k = idx / C, c = idx % C;
        float v = S[(size_t)k * C + c];
        ushort hi = bf16_rn(v);
        ushort lo = bf16_rn(v - bf16_f(hi));
        int pos = c * 128 + ((((k >> 3) ^ (c & 15)) << 3) | (k & 7));
        DH[pos] = hi; DL[pos] = lo;
    }
}

// ---------------------------------------------------------------------------
// MFMA GEMM (split-bf16): out[n] = [relu](agg[n] @ W[t] + b[t]) [* dropout]
// A fragments loaded DIRECTLY from global (no cross-lane reuse -> no LDS);
// only W (+ND) staged in LDS: 64.5KB @DOUT=128 -> 2 blocks/CU, 4 waves/SIMD.
// ---------------------------------------------------------------------------
template<int DOUT, bool RELU, bool DROP, bool OUTBF>
__global__ __launch_bounds__(512) void mfma_gemm_kernel(
    const uint32_t* __restrict__ agghi, const uint32_t* __restrict__ agglo,
    const int* __restrict__ order, const int* __restrict__ off,
    const ushort* __restrict__ WThi, const ushort* __restrict__ WTlo,
    const float* __restrict__ bias8, void* __restrict__ houtv,
    uint32_t fk0, uint32_t fk1)
{
    __shared__ ushort WH[DOUT * 128];
    __shared__ ushort WL[DOUT * 128];
    __shared__ int ND[128];

    int b0 = blockIdx.x * 128;
    if (b0 >= off[8]) return;
    int t = 0;
    #pragma unroll
    for (int u = 1; u < 8; ++u) if (b0 >= off[u]) ++t;
    int tid = threadIdx.x;

    if (tid < 128) ND[tid] = order[b0 + tid];

    // stage W (pre-transposed, pre-swizzled -> straight copy)
    {
        const float4* sh = (const float4*)(WThi + (size_t)t * DOUT * 128);
        const float4* sl = (const float4*)(WTlo + (size_t)t * DOUT * 128);
        float4* dh = (float4*)WH; float4* dl = (float4*)WL;
        #pragma unroll
        for (int it = 0; it < DOUT * 16 / 512; ++it) {
            int c = it * 512 + tid;
            dh[c] = sh[c]; dl[c] = sl[c];
        }
    }
    __syncthreads();

    int wid = tid >> 6, lane = tid & 63;
    int r15 = lane & 15, q = lane >> 4;
    int arow = wid * 16 + r15;
    int nd_a = ND[arow];

    // A fragments straight from global (agg is L3-resident)
    const bf16x8* gh = (const bf16x8*)agghi;
    const bf16x8* gl = (const bf16x8*)agglo;
    bf16x8 zero8 = (bf16x8){0, 0, 0, 0, 0, 0, 0, 0};
    bf16x8 ahv[4], alv[4];
    {
        size_t rowb = (size_t)(nd_a < 0 ? 0 : nd_a) * 16;
        #pragma unroll
        for (int ks = 0; ks < 4; ++ks) {
            size_t ix = rowb + (q + ks * 4);
            ahv[ks] = (nd_a >= 0) ? gh[ix] : zero8;
            alv[ks] = (nd_a >= 0) ? gl[ix] : zero8;
        }
    }

    constexpr int NF = DOUT / 16;
    f32x4 acc[NF];
    #pragma unroll
    for (int i = 0; i < NF; ++i) acc[i] = (f32x4){0.f, 0.f, 0.f, 0.f};

    const bf16x8* WHp = (const bf16x8*)WH;
    const bf16x8* WLp = (const bf16x8*)WL;

    #pragma unroll
    for (int ks = 0; ks < 4; ++ks) {
        int sch = (q + ks * 4) ^ r15;
        bf16x8 ah = ahv[ks];
        bf16x8 al = alv[ks];
        #pragma unroll
        for (int nf = 0; nf < NF; ++nf) {
            int col = nf * 16 + r15;
            bf16x8 bh = WHp[col * 16 + sch];
            bf16x8 bl = WLp[col * 16 + sch];
            acc[nf] = __builtin_amdgcn_mfma_f32_16x16x32_bf16(ah, bh, acc[nf], 0, 0, 0);
            acc[nf] = __builtin_amdgcn_mfma_f32_16x16x32_bf16(ah, bl, acc[nf], 0, 0, 0);
            acc[nf] = __builtin_amdgcn_mfma_f32_16x16x32_bf16(al, bh, acc[nf], 0, 0, 0);
        }
    }

    // epilogue: C/D row = wid*16 + q*4 + r, col = nf*16 + r15
    int ndr[4];
    #pragma unroll
    for (int r = 0; r < 4; ++r) ndr[r] = ND[wid * 16 + q * 4 + r];
    const float* bptr = bias8 + (size_t)t * DOUT;

    #pragma unroll
    for (int nf = 0; nf < NF; ++nf) {
        int col = nf * 16 + r15;
        float bv = bptr[col];
        float vr[4];
        #pragma unroll
        for (int r = 0; r < 4; ++r) {
            float v = acc[nf][r] + bv;
            if (RELU) v = fmaxf(v, 0.f);
            if (DROP) {
                int nd = ndr[r] < 0 ? 0 : ndr[r];
                v *= drop_scale(fk0, fk1, (uint32_t)nd * 128u + (uint32_t)col);
            }
            vr[r] = v;
        }
        if (OUTBF) {
            uint32_t* hb = (uint32_t*)houtv;
            #pragma unroll
            for (int r = 0; r < 4; ++r) {
                float w = __shfl_xor(vr[r], 1, 64);
                if ((lane & 1) == 0 && ndr[r] >= 0)
                    hb[(size_t)ndr[r] * (DOUT / 2) + (col >> 1)] = pack2bf(vr[r], w);
            }
        } else {
            float* ho = (float*)houtv;
            #pragma unroll
            for (int r = 0; r < 4; ++r)
                if (ndr[r] >= 0) ho[(size_t)ndr[r] * DOUT + col] = vr[r];
        }
    }
}

// ---------------------------------------------------------------------------
// fc fusion: Wf[t] = W[t] @ fcW (128x64 f32), bf[t] = b[t] @ fcW + fcb
// ---------------------------------------------------------------------------
__global__ __launch_bounds__(256) void fuse_fc_kernel(
    const float* __restrict__ convW, const float* __restrict__ convb,
    const float* __restrict__ fcW, const float* __restrict__ fcb,
    float* __restrict__ Wf, float* __restrict__ bf)
{
    __shared__ float F[128 * 64];
    int t = blockIdx.x, tid = threadIdx.x;
    #pragma unroll
    for (int it = 0; it < 8; ++it) {
        int idx4 = (it * 256 + tid) * 4;
        *(float4*)&F[idx4] = *(const float4*)&fcW[idx4];
    }
    __syncthreads();

    int r = tid >> 1, cb = (tid & 1) * 32;
    const float* Wrow = convW + (size_t)t * 16384 + (size_t)r * 128;
    float acc[32];
    #pragma unroll
    for (int c = 0; c < 32; ++c) acc[c] = 0.f;
    for (int k = 0; k < 128; ++k) {
        float w = Wrow[k];
        #pragma unroll
        for (int c = 0; c < 32; ++c) acc[c] += w * F[k * 64 + cb + c];
    }
    float* outp = Wf + (size_t)t * 8192 + (size_t)r * 64 + cb;
    #pragma unroll
    for (int c = 0; c < 32; ++c) outp[c] = acc[c];

    if (tid < 64) {
        float a = fcb[tid];
        const float* bt = convb + (size_t)t * 128;
        for (int k = 0; k < 128; ++k) a += bt[k] * F[k * 64 + tid];
        bf[(size_t)t * 64 + tid] = a;
    }
}

// ---------------------------------------------------------------------------
extern "C" void kernel_launch(void* const* d_in, const int* in_sizes, int n_in,
                              void* d_out, int out_size, void* d_ws, size_t ws_size,
                              hipStream_t stream)
{
    const float* features = (const float*)d_in[0];
    const int*   src0 = (const int*)d_in[1];
    const int*   dst0 = (const int*)d_in[2];
    const int*   types1 = (const int*)d_in[3];
    const int*   src1 = (const int*)d_in[4];
    const int*   dst1 = (const int*)d_in[5];
    const int*   types2 = (const int*)d_in[6];
    const int*   src2 = (const int*)d_in[7];
    const int*   dst2 = (const int*)d_in[8];
    const int*   types3 = (const int*)d_in[9];
    const float* convW = (const float*)d_in[10];
    const float* convb = (const float*)d_in[11];
    const float* fcW   = (const float*)d_in[12];
    const float* fcb   = (const float*)d_in[13];

    int N0 = in_sizes[0] / 128;
    int E0 = in_sizes[1], N1 = in_sizes[3];
    int E1 = in_sizes[4], N2 = in_sizes[6];
    int E2 = in_sizes[7], N3 = in_sizes[9];
    int totalN = N1 + N2 + N3;
    int totalE = E0 + E1 + E2;
    int r1 = N1 + 1, r2 = N1 + 1 + N2 + 1;           // rowptr offsets
    int no1p = N1 + 1024, no2p = no1p + N2 + 1024;   // padded order3 offsets
    int maxN = N1 > N2 ? N1 : N2; if (N3 > maxN) maxN = N3;

    // bucket-sort geometry
    int nb0 = (N1 + 1023) >> 10, nb1 = (N2 + 1023) >> 10, nb2 = (N3 + 1023) >> 10;
    int TB = nb0 + nb1 + nb2;
    int nblk0 = (E0 + EPB - 1) / EPB, nblk1 = (E1 + EPB - 1) / EPB, nblk2 = (E2 + EPB - 1) / EPB;
    int nblkMax = nblk0 > nblk1 ? nblk0 : nblk1; if (nblk2 > nblkMax) nblkMax = nblk2;
    int cO0 = 0;
    int cO1 = cO0 + nblk0 * nb0;
    int cO2 = cO1 + nblk1 * nb1;
    int cntEntries = cO2 + nblk2 * nb2;

    char* ws = (char*)d_ws;
    size_t woff = 0;
    auto alloc = [&](size_t bytes) -> void* {
        void* p = ws + woff;
        woff = (woff + bytes + 255) & ~(size_t)255;
        return p;
    };
    uint32_t* fbf     = (uint32_t*)alloc((size_t)N0 * 64 * 4);    // packed bf16 features
    uint32_t* hbf     = fbf;                                      // alias: h after L0 agg
    uint32_t* aggHi   = (uint32_t*)alloc((size_t)maxN * 64 * 4);
    uint32_t* pairs   = aggHi;                                    // alias: dead before agg
    uint32_t* aggLo   = (uint32_t*)alloc((size_t)maxN * 64 * 4);
    uint32_t* rowptr3 = (uint32_t*)alloc((size_t)(totalN + 3) * 4);
    int*      elist3  = (int*)alloc((size_t)totalE * 4);
    int*      order3  = (int*)alloc((size_t)(totalN + 3 * 1024) * 4);
    uint32_t* cnt     = (uint32_t*)alloc((size_t)cntEntries * 4);
    uint32_t* bo      = (uint32_t*)alloc((size_t)(TB + 3) * 4);
    uint32_t* tcnt    = (uint32_t*)alloc(24 * 4);
    int*      boff    = (int*)alloc(27 * 4);
    uint32_t* tcur    = (uint32_t*)alloc(24 * 4);
    float*    Wf      = (float*)alloc((size_t)8 * 128 * 64 * 4);
    float*    bfb     = (float*)alloc((size_t)8 * 64 * 4);
    ushort*   WThi    = (ushort*)alloc((size_t)8 * 128 * 128 * 2);
    ushort*   WTlo    = (ushort*)alloc((size_t)8 * 128 * 128 * 2);
    ushort*   WfThi   = (ushort*)alloc((size_t)8 * 64 * 128 * 2);
    ushort*   WfTlo   = (ushort*)alloc((size_t)8 * 64 * 128 * 2);
    (void)ws_size; (void)n_in; (void)out_size;

    // --- one-time prep ---
    fcvt_kernel<<<4096, 256, 0, stream>>>(
        (const float4*)features, (uint2*)fbf, (long long)N0 * 32);
    prep_wt_kernel<<<8, 256, 0, stream>>>(convW, WThi, WTlo, 128);
    fuse_fc_kernel<<<8, 256, 0, stream>>>(convW, convb, fcW, fcb, Wf, bfb);
    prep_wt_kernel<<<8, 256, 0, stream>>>(Wf, WfThi, WfTlo, 64);

    // --- bucketed CSR build (no global atomics) ---
    bcount3_kernel<<<dim3(nblkMax, 3), 256, 0, stream>>>(
        dst0, dst1, dst2, E0, E1, E2, nb0, nb1, nb2,
        nblk0, nblk1, nblk2, cO0, cO1, cO2, cnt);
    bscan_kernel<<<1, 512, 0, stream>>>(cnt, bo, rowptr3,
        nb0, nb1, nb2, nblk0, nblk1, nblk2, cO0, cO1, cO2, N1, N2, N3, r1, r2);
    brebase_kernel<<<(TB + 255) / 256, 256, 0, stream>>>(bo, cnt,
        nb0, nb1, nb2, nblk0, nblk1, nblk2, cO0, cO1, cO2);
    bscatter3_kernel<<<dim3(nblkMax, 3), 256, 0, stream>>>(
        src0, dst0, src1, dst1, src2, dst2, E0, E1, E2, nb0, nb1, nb2,
        nblk0, nblk1, nblk2, cO0, cO1, cO2, cnt, pairs);
    bfill_kernel<<<TB, 256, 0, stream>>>(bo, pairs, elist3, rowptr3,
        nb0, nb1, nb2, N1, N2, N3, E0, E1, r1, r2);

    // --- batched type bucketing (padded bins) ---
    hipMemsetAsync(tcnt, 0, 24 * 4, stream);
    int nblkT = (totalN + 255) / 256;
    count3_kernel<<<nblkT, 256, 0, stream>>>(types1, types2, types3, N1, N2, N3, tcnt);
    scan_types3_kernel<<<1, 256, 0, stream>>>(tcnt, boff, tcur, order3, no1p, no2p);
    order3_kernel<<<nblkT, 256, 0, stream>>>(
        types1, types2, types3, N1, N2, N3, tcur, order3, no1p, no2p);

    // fold-in keys
    uint32_t fk1a, fk1b, fk2a, fk2b;
    tf2x32(0u, 42u, 0u, 1u, &fk1a, &fk1b);
    tf2x32(0u, 42u, 0u, 2u, &fk2a, &fk2b);

    // --- layer 0 ---
    aggregate_kernel<<<(N1 + 7) / 8, 256, 0, stream>>>(
        fbf, rowptr3, elist3, aggHi, aggLo, N1);
    mfma_gemm_kernel<128, true, true, true><<<(N1 + 127) / 128 + 8, 512, 0, stream>>>(
        aggHi, aggLo, order3, boff, WThi, WTlo, convb, hbf, fk1a, fk1b);

    // --- layer 1 ---
    aggregate_kernel<<<(N2 + 7) / 8, 256, 0, stream>>>(
        hbf, rowptr3 + r1, elist3 + E0, aggHi, aggLo, N2);
    mfma_gemm_kernel<128, true, true, true><<<(N2 + 127) / 128 + 8, 512, 0, stream>>>(
        aggHi, aggLo, order3 + no1p, boff + 9, WThi, WTlo, convb, hbf, fk2a, fk2b);

    // --- layer 2 (fc folded, f32 out) ---
    aggregate_kernel<<<(N3 + 7) / 8, 256, 0, stream>>>(
        hbf, rowptr3 + r2, elist3 + E0 + E1, aggHi, aggLo, N3);
    mfma_gemm_kernel<64, false, false, false><<<(N3 + 127) / 128 + 8, 512, 0, stream>>>(
        aggHi, aggLo, order3 + no2p, boff + 18, WfThi, WfTlo, bfb, d_out, 0u, 0u);
}